// Round 13
// baseline (1520.567 us; speedup 1.0000x reference)
//
#include <hip/hip_runtime.h>
#include <hip/hip_bf16.h>
#include <math.h>

#define Bb   32
#define Ll   30
#define Hh   300
#define Pp   8
#define Nn   16384
#define Ee   131072
#define NPG  512
#define NI   5

typedef __attribute__((ext_vector_type(4))) float f32x4;
typedef __attribute__((ext_vector_type(8))) short s16x8;

__device__ __forceinline__ float eluf(float x){ return x > 0.f ? x : expm1f(x); }
__device__ __forceinline__ float sigf(float x){ return 1.f/(1.f+expf(-x)); }
__device__ __forceinline__ float wave_sum(float s){
    s += __shfl_xor(s, 32); s += __shfl_xor(s, 16); s += __shfl_xor(s, 8);
    s += __shfl_xor(s, 4);  s += __shfl_xor(s, 2);  s += __shfl_xor(s, 1);
    return s;
}
__device__ __forceinline__ unsigned short f2bf(float x){
    unsigned u = __float_as_uint(x);
    unsigned r = u + 0x7FFFu + ((u >> 16) & 1u);
    return (unsigned short)(r >> 16);
}
__device__ __forceinline__ float bf2f(unsigned short v){
    return __uint_as_float(((unsigned)v) << 16);
}
__device__ __forceinline__ float bflo(unsigned w){ return __uint_as_float(w << 16); }
__device__ __forceinline__ float bfhi(unsigned w){ return __uint_as_float(w & 0xFFFF0000u); }

// ---------------------------------------------------------------------------
// A-tile fetch
// ---------------------------------------------------------------------------
template<int KK, bool BFA>
__device__ __forceinline__ void fetch_as(const float* __restrict__ arowf,
                                         const unsigned short* __restrict__ arowb,
                                         const float* __restrict__ srow,
                                         int k, float* a8, float* s8)
{
    if constexpr (BFA) {
        s16x8 av = *(const s16x8*)(arowb + k);
        float4 w0 = *(const float4*)(srow + k), w1 = *(const float4*)(srow + k + 4);
        s8[0]=w0.x; s8[1]=w0.y; s8[2]=w0.z; s8[3]=w0.w; s8[4]=w1.x; s8[5]=w1.y; s8[6]=w1.z; s8[7]=w1.w;
        #pragma unroll
        for (int j = 0; j < 8; j++) a8[j] = bf2f((unsigned short)av[j]);
    } else {
        if (k + 8 <= KK) {
            float4 v0 = *(const float4*)(arowf + k), v1 = *(const float4*)(arowf + k + 4);
            a8[0]=v0.x; a8[1]=v0.y; a8[2]=v0.z; a8[3]=v0.w; a8[4]=v1.x; a8[5]=v1.y; a8[6]=v1.z; a8[7]=v1.w;
            float4 w0 = *(const float4*)(srow + k), w1 = *(const float4*)(srow + k + 4);
            s8[0]=w0.x; s8[1]=w0.y; s8[2]=w0.z; s8[3]=w0.w; s8[4]=w1.x; s8[5]=w1.y; s8[6]=w1.z; s8[7]=w1.w;
        } else {
            #pragma unroll
            for (int j = 0; j < 8; j++){ int kk = k + j; a8[j] = (kk < KK) ? arowf[kk] : 0.f; s8[j] = (kk < KK) ? srow[kk] : 0.f; }
        }
    }
}

// ---------------------------------------------------------------------------
// MFMA scored-GEMM (4 waves = 4 col quarters, 64 rows each)
// ---------------------------------------------------------------------------
template<int KK, int BPITCH, int NTILES, bool BFA>
__device__ __forceinline__ void mfma_score_impl(
    const float* __restrict__ Af, const unsigned short* __restrict__ Ab, int lda,
    const unsigned short* __restrict__ Bt,
    const float* __restrict__ S, int sstride, const int* __restrict__ rowb,
    const float* __restrict__ wpad,
    float* __restrict__ out)
{
    __shared__ unsigned short As[2][64*40];
    __shared__ unsigned short Bs[2][304*40];
    __shared__ float red[4][64];

    const int t = threadIdx.x;
    const int wc = t >> 6, lane = t & 63;
    const int l15 = lane & 15, g = lane >> 4;
    const int rowBlock = blockIdx.x * 64;

    const int sr = t >> 2;
    const int sk = (t & 3) * 8;
    const int grow = rowBlock + sr;
    const int bb = rowb[grow];
    const float* arowf = nullptr;
    const unsigned short* arowb = nullptr;
    if constexpr (BFA) arowb = Ab + (size_t)grow * lda;
    else               arowf = Af + (size_t)grow * lda;
    const float* srow = S + (size_t)bb * sstride;

    f32x4 acc[4][5];
    #pragma unroll
    for (int rt = 0; rt < 4; rt++)
        #pragma unroll
        for (int ct = 0; ct < 5; ct++) acc[rt][ct] = (f32x4){0.f,0.f,0.f,0.f};

    float a8[8], s8[8];
    s16x8 bvec[5];

    {
        fetch_as<KK, BFA>(arowf, arowb, srow, sk, a8, s8);
        #pragma unroll
        for (int i = 0; i < 5; i++){
            int v = t + 256 * i;
            if (v < 1216) bvec[i] = *(const s16x8*)&Bt[(size_t)(v >> 2) * BPITCH + ((v & 3) * 8)];
        }
        s16x8 pv;
        #pragma unroll
        for (int j = 0; j < 8; j++) pv[j] = (short)f2bf(a8[j] * s8[j]);
        *(s16x8*)&As[0][sr * 40 + sk] = pv;
        #pragma unroll
        for (int i = 0; i < 5; i++){
            int v = t + 256 * i;
            if (v < 1216) *(s16x8*)&Bs[0][(v >> 2) * 40 + ((v & 3) * 8)] = bvec[i];
        }
    }
    __syncthreads();

    int cur = 0;
    for (int kt = 0; kt < NTILES; ++kt) {
        if (kt + 1 < NTILES) {
            fetch_as<KK, BFA>(arowf, arowb, srow, (kt + 1) * 32 + sk, a8, s8);
            int k0 = (kt + 1) * 32;
            #pragma unroll
            for (int i = 0; i < 5; i++){
                int v = t + 256 * i;
                if (v < 1216) bvec[i] = *(const s16x8*)&Bt[(size_t)(v >> 2) * BPITCH + k0 + ((v & 3) * 8)];
            }
        }
        s16x8 af[4];
        #pragma unroll
        for (int rt = 0; rt < 4; rt++)
            af[rt] = *(s16x8*)&As[cur][(rt * 16 + l15) * 40 + g * 8];
        #pragma unroll
        for (int ct = 0; ct < 5; ct++) {
            if (wc == 3 && ct == 4) continue;
            int col = wc * 80 + ct * 16 + l15;
            s16x8 bf = *(s16x8*)&Bs[cur][col * 40 + g * 8];
            #pragma unroll
            for (int rt = 0; rt < 4; rt++)
                acc[rt][ct] = __builtin_amdgcn_mfma_f32_16x16x32_bf16(af[rt], bf, acc[rt][ct], 0, 0, 0);
        }
        if (kt + 1 < NTILES) {
            s16x8 pv;
            #pragma unroll
            for (int j = 0; j < 8; j++) pv[j] = (short)f2bf(a8[j] * s8[j]);
            *(s16x8*)&As[cur ^ 1][sr * 40 + sk] = pv;
            #pragma unroll
            for (int i = 0; i < 5; i++){
                int v = t + 256 * i;
                if (v < 1216) *(s16x8*)&Bs[cur ^ 1][(v >> 2) * 40 + ((v & 3) * 8)] = bvec[i];
            }
        }
        __syncthreads();
        cur ^= 1;
    }

    float p[4][4];
    #pragma unroll
    for (int rt = 0; rt < 4; rt++)
        #pragma unroll
        for (int i = 0; i < 4; i++) p[rt][i] = 0.f;
    #pragma unroll
    for (int ct = 0; ct < 5; ct++) {
        if (wc == 3 && ct == 4) continue;
        int col = wc * 80 + ct * 16 + l15;
        float wv = wpad[col];
        #pragma unroll
        for (int rt = 0; rt < 4; rt++)
            #pragma unroll
            for (int i = 0; i < 4; i++)
                p[rt][i] += eluf(acc[rt][ct][i]) * wv;
    }
    #pragma unroll
    for (int m = 1; m <= 8; m <<= 1) {
        #pragma unroll
        for (int rt = 0; rt < 4; rt++)
            #pragma unroll
            for (int i = 0; i < 4; i++)
                p[rt][i] += __shfl_xor(p[rt][i], m);
    }
    if (l15 == 0) {
        #pragma unroll
        for (int rt = 0; rt < 4; rt++)
            #pragma unroll
            for (int i = 0; i < 4; i++)
                red[wc][rt * 16 + g * 4 + i] = p[rt][i];
    }
    __syncthreads();
    if (t < 64)
        out[rowBlock + t] = red[0][t] + red[1][t] + red[2][t] + red[3][t];
}

// Batched over steps: blockIdx.y = step (0..3)
__global__ __launch_bounds__(256, 2) void mfma_node_k(
    const unsigned short* __restrict__ Ab, const unsigned short* __restrict__ Bt,
    const float* __restrict__ iscl4, const int* __restrict__ rowb,
    const float* __restrict__ wpad, float* __restrict__ nsc4)
{
    const int step = blockIdx.y;
    mfma_score_impl<2400, 2400, 75, true>(nullptr, Ab, 2400, Bt,
        iscl4 + (size_t)step * Bb * 2400, 2400, rowb, wpad,
        nsc4 + (size_t)step * Nn);
}
__global__ __launch_bounds__(256, 2) void mfma_edge_k(
    const unsigned short* __restrict__ Ab, const unsigned short* __restrict__ Bt,
    const float* __restrict__ instr, const int* __restrict__ rowb,
    const float* __restrict__ wpad, float* __restrict__ es4)
{
    const int step = blockIdx.y;
    mfma_score_impl<320, 320, 10, true>(nullptr, Ab, 320, Bt,
        instr + step * 300, NI * 300, rowb, wpad,
        es4 + (size_t)step * Ee);
}
__global__ __launch_bounds__(256, 2) void mfma_node_f_k(
    const float* __restrict__ A, const unsigned short* __restrict__ Bt,
    const float* __restrict__ iscl4, const int* __restrict__ rowb,
    const float* __restrict__ wpad, float* __restrict__ nsc4)
{
    const int step = blockIdx.y;
    mfma_score_impl<2400, 2400, 75, false>(A, nullptr, 2400, Bt,
        iscl4 + (size_t)step * Bb * 2400, 2400, rowb, wpad,
        nsc4 + (size_t)step * Nn);
}
__global__ __launch_bounds__(256, 2) void mfma_edge_f_k(
    const float* __restrict__ A, const unsigned short* __restrict__ Bt,
    const float* __restrict__ instr, const int* __restrict__ rowb,
    const float* __restrict__ wpad, float* __restrict__ es4)
{
    const int step = blockIdx.y;
    mfma_score_impl<300, 320, 10, false>(A, nullptr, 300, Bt,
        instr + step * 300, NI * 300, rowb, wpad,
        es4 + (size_t)step * Ee);
}

// ---------------------------------------------------------------------------
// Generic MFMA GEMM. Optional fused add: C += simlast[row*2001] * qm[row*300+col]
// ---------------------------------------------------------------------------
__global__ __launch_bounds__(256, 2) void mfma_gemm_k(
    const float* __restrict__ A, int lda, int K, int ntiles,
    const unsigned short* __restrict__ Bt, int bpitch,
    int ncols, float* __restrict__ C, int ldc,
    const float* __restrict__ simlast, const float* __restrict__ qm)
{
    __shared__ unsigned short As[2][64*40];
    __shared__ unsigned short Bs[2][304*40];

    const int t = threadIdx.x;
    const int wc = t >> 6, lane = t & 63;
    const int l15 = lane & 15, g = lane >> 4;
    const int rowBlock = blockIdx.x * 64;
    const int colBlock = blockIdx.y * 304;

    const int sr = t >> 2, sk = (t & 3) * 8;
    const float* arow = A + (size_t)(rowBlock + sr) * lda;

    f32x4 acc[4][5];
    #pragma unroll
    for (int rt = 0; rt < 4; rt++)
        #pragma unroll
        for (int ct = 0; ct < 5; ct++) acc[rt][ct] = (f32x4){0.f,0.f,0.f,0.f};

    float a8[8];
    s16x8 bvec[5];

    {
        int k = sk;
        if (k + 8 <= K) {
            float4 v0 = *(const float4*)(arow + k), v1 = *(const float4*)(arow + k + 4);
            a8[0]=v0.x; a8[1]=v0.y; a8[2]=v0.z; a8[3]=v0.w; a8[4]=v1.x; a8[5]=v1.y; a8[6]=v1.z; a8[7]=v1.w;
        } else {
            #pragma unroll
            for (int j = 0; j < 8; j++){ int kk = k + j; a8[j] = (kk < K) ? arow[kk] : 0.f; }
        }
        #pragma unroll
        for (int i = 0; i < 5; i++){
            int v = t + 256 * i;
            if (v < 1216) bvec[i] = *(const s16x8*)&Bt[(size_t)(colBlock + (v >> 2)) * bpitch + ((v & 3) * 8)];
        }
        s16x8 pv;
        #pragma unroll
        for (int j = 0; j < 8; j++) pv[j] = (short)f2bf(a8[j]);
        *(s16x8*)&As[0][sr * 40 + sk] = pv;
        #pragma unroll
        for (int i = 0; i < 5; i++){
            int v = t + 256 * i;
            if (v < 1216) *(s16x8*)&Bs[0][(v >> 2) * 40 + ((v & 3) * 8)] = bvec[i];
        }
    }
    __syncthreads();

    int cur = 0;
    for (int kt = 0; kt < ntiles; ++kt) {
        if (kt + 1 < ntiles) {
            int k = (kt + 1) * 32 + sk;
            if (k + 8 <= K) {
                float4 v0 = *(const float4*)(arow + k), v1 = *(const float4*)(arow + k + 4);
                a8[0]=v0.x; a8[1]=v0.y; a8[2]=v0.z; a8[3]=v0.w; a8[4]=v1.x; a8[5]=v1.y; a8[6]=v1.z; a8[7]=v1.w;
            } else {
                #pragma unroll
                for (int j = 0; j < 8; j++){ int kk = k + j; a8[j] = (kk < K) ? arow[kk] : 0.f; }
            }
            int k0 = (kt + 1) * 32;
            #pragma unroll
            for (int i = 0; i < 5; i++){
                int v = t + 256 * i;
                if (v < 1216) bvec[i] = *(const s16x8*)&Bt[(size_t)(colBlock + (v >> 2)) * bpitch + k0 + ((v & 3) * 8)];
            }
        }
        s16x8 af[4];
        #pragma unroll
        for (int rt = 0; rt < 4; rt++)
            af[rt] = *(s16x8*)&As[cur][(rt * 16 + l15) * 40 + g * 8];
        #pragma unroll
        for (int ct = 0; ct < 5; ct++) {
            if (wc == 3 && ct == 4) continue;
            int col = wc * 80 + ct * 16 + l15;
            s16x8 bf = *(s16x8*)&Bs[cur][col * 40 + g * 8];
            #pragma unroll
            for (int rt = 0; rt < 4; rt++)
                acc[rt][ct] = __builtin_amdgcn_mfma_f32_16x16x32_bf16(af[rt], bf, acc[rt][ct], 0, 0, 0);
        }
        if (kt + 1 < ntiles) {
            s16x8 pv;
            #pragma unroll
            for (int j = 0; j < 8; j++) pv[j] = (short)f2bf(a8[j]);
            *(s16x8*)&As[cur ^ 1][sr * 40 + sk] = pv;
            #pragma unroll
            for (int i = 0; i < 5; i++){
                int v = t + 256 * i;
                if (v < 1216) *(s16x8*)&Bs[cur ^ 1][(v >> 2) * 40 + ((v & 3) * 8)] = bvec[i];
            }
        }
        __syncthreads();
        cur ^= 1;
    }

    #pragma unroll
    for (int ct = 0; ct < 5; ct++) {
        if (wc == 3 && ct == 4) continue;
        int col = colBlock + wc * 80 + ct * 16 + l15;
        if (col >= ncols) continue;
        #pragma unroll
        for (int rt = 0; rt < 4; rt++) {
            int row0 = rowBlock + rt * 16 + g * 4;
            #pragma unroll
            for (int i = 0; i < 4; i++) {
                float v = acc[rt][ct][i];
                int row = row0 + i;
                if (simlast) v += simlast[(size_t)row * 2001] * qm[(size_t)row * 300 + col];
                C[(size_t)row * ldc + col] = v;
            }
        }
    }
}

// ---------------------------------------------------------------------------
// ONE prep kernel: all weight-table builds (flat-index range dispatch).
// ---------------------------------------------------------------------------
#define R_BTN   729600              // btn:  304x2400
#define R_BTE   (R_BTN + 97280)     // bte:  304x320
#define R_BTQ   (R_BTE + 97280)     // btq:  304x320
#define R_BTV   (R_BTQ + 680960)    // btv:  2128x320
#define R_BTC   (R_BTV + 612864)    // btc:  304x2016
#define R_BTW   (R_BTC + 389120)    // btw:  1216x320
#define R_WL    (R_BTW + 360000)    // wlstm: 300x1200
#define R_RWH   (R_WL + 90000)      // rwhhT
#define R_RWI   (R_RWH + 90000)     // rwihT
#define R_WP    (R_RWI + 608)       // wpad 2x304
#define R_TOTAL R_WP

__global__ void prep_all_k(
    const float* __restrict__ Wnp, const float* __restrict__ Wedge,
    const float* __restrict__ tagger_weight, const float* __restrict__ cv,
    const float* __restrict__ td, const float* __restrict__ lstm_Wih,
    const float* __restrict__ lstm_Whh, const float* __restrict__ rnn_Whh,
    const float* __restrict__ rnn_Wih, const float* __restrict__ wn,
    const float* __restrict__ wr,
    unsigned short* __restrict__ btn, unsigned short* __restrict__ bte,
    unsigned short* __restrict__ btq, unsigned short* __restrict__ btv,
    unsigned short* __restrict__ btc, unsigned short* __restrict__ btw,
    unsigned short* __restrict__ wlstm, float* __restrict__ rwhhT,
    float* __restrict__ rwihT, float* __restrict__ wnp, float* __restrict__ wrp)
{
    int idx = blockIdx.x * 256 + threadIdx.x;
    if (idx >= R_TOTAL) return;
    if (idx < R_BTN) {
        int col = idx / 2400, k = idx - col * 2400;
        btn[idx] = f2bf((col < 300) ? Wnp[(size_t)k * 300 + col] : 0.f);
    } else if (idx < R_BTE) {
        int r = idx - R_BTN;
        int col = r / 320, k = r - col * 320;
        bte[r] = f2bf((col < 300 && k < 300) ? Wedge[(size_t)k * 300 + col] : 0.f);
    } else if (idx < R_BTQ) {
        int r = idx - R_BTE;
        int col = r / 320, k = r - col * 320;
        btq[r] = f2bf((col < 300 && k < 300) ? tagger_weight[(size_t)k * 300 + col] : 0.f);
    } else if (idx < R_BTV) {
        int r = idx - R_BTQ;
        int col = r / 320, k = r - col * 320;
        float v = 0.f;
        if (k < 300) {
            if (col < 2000) v = cv[(size_t)col * 300 + k];
            else if (col == 2000) v = td[k];
        }
        btv[r] = f2bf(v);
    } else if (idx < R_BTC) {
        int r = idx - R_BTV;
        int col = r / 2016, k = r - col * 2016;
        btc[r] = f2bf((col < 300 && k < 2000) ? cv[(size_t)k * 300 + col] : 0.f);
    } else if (idx < R_BTW) {
        int r = idx - R_BTC;
        int col = r / 320, k = r - col * 320;
        btw[r] = f2bf((col < 1200 && k < 300) ? lstm_Wih[(size_t)col * 300 + k] : 0.f);
    } else if (idx < R_WL) {
        int r = idx - R_BTW;
        int k = r / 1200, row = r - k * 1200;
        wlstm[r] = f2bf(lstm_Whh[(size_t)row * 300 + k]);
    } else if (idx < R_RWH) {
        int r = idx - R_WL;
        int row = r / 300, c = r - row * 300;
        rwhhT[(size_t)c * 300 + row] = rnn_Whh[r];
    } else if (idx < R_RWI) {
        int r = idx - R_RWH;
        int row = r / 300, c = r - row * 300;
        rwihT[(size_t)c * 300 + row] = rnn_Wih[r];
    } else {
        int r = idx - R_RWI;
        if (r < 304) wnp[r] = (r < 300) ? wn[r] : 0.f;
        else { int r2 = r - 304; wrp[r2] = (r2 < 300) ? wr[r2] : 0.f; }
    }
}

// ONE convert kernel for both attr arrays (grid-stride over vec8 groups)
__global__ void cvt_both_k(const float* __restrict__ na, const float* __restrict__ ea,
                           unsigned short* __restrict__ nab, unsigned short* __restrict__ eab)
{
    const long NG = (long)Nn * 300;
    const long EG = (long)Ee * 40;
    const long total = NG + EG;
    for (long i = (long)blockIdx.x * blockDim.x + threadIdx.x; i < total;
         i += (long)gridDim.x * blockDim.x) {
        if (i < NG) {
            long base = i * 8;
            float4 v0 = *(const float4*)(na + base);
            float4 v1 = *(const float4*)(na + base + 4);
            s16x8 v;
            v[0]=(short)f2bf(v0.x); v[1]=(short)f2bf(v0.y); v[2]=(short)f2bf(v0.z); v[3]=(short)f2bf(v0.w);
            v[4]=(short)f2bf(v1.x); v[5]=(short)f2bf(v1.y); v[6]=(short)f2bf(v1.z); v[7]=(short)f2bf(v1.w);
            *(s16x8*)&nab[base] = v;
        } else {
            long r2 = i - NG;
            long row = r2 / 40;
            int kg = (int)(r2 - row * 40) * 8;
            s16x8 v;
            #pragma unroll
            for (int j = 0; j < 8; j++){
                int k = kg + j;
                float x = (k < 300) ? ea[row * 300 + k] : 0.f;
                v[j] = (short)f2bf(x);
            }
            *(s16x8*)&eab[row * 320 + kg] = v;
        }
    }
}

// dist = 1/512, msgdot = 0, agg = 0 (one launch)
__global__ void init_k(float* __restrict__ dist, float* __restrict__ msgdot,
                       float* __restrict__ agg)
{
    int n = blockIdx.x * 256 + threadIdx.x;
    if (n < Nn) { dist[n] = 1.f / (float)NPG; msgdot[n] = 0.f; }
    if (n < 9600) agg[n] = 0.f;
}

// ---------------------------------------------------------------------------
__global__ void softmax_rows_k(float* __restrict__ X, int nc)
{
    int row = blockIdx.x, t = threadIdx.x;
    __shared__ float red[256];
    size_t base = (size_t)row * nc;
    float m = -3.4e38f;
    for (int i = t; i < nc; i += 256) m = fmaxf(m, X[base + i]);
    red[t] = m; __syncthreads();
    for (int s = 128; s > 0; s >>= 1){ if (t < s) red[t] = fmaxf(red[t], red[t+s]); __syncthreads(); }
    float mx = red[0]; __syncthreads();
    float sm = 0.f;
    for (int i = t; i < nc; i += 256){ float e = expf(X[base + i] - mx); X[base + i] = e; sm += e; }
    red[t] = sm; __syncthreads();
    for (int s = 128; s > 0; s >>= 1){ if (t < s) red[t] += red[t+s]; __syncthreads(); }
    float inv = 1.f / red[0];
    for (int i = t; i < nc; i += 256) X[base + i] *= inv;
}

// ---------------------------------------------------------------------------
// LSTM v3: cooperative double-buffered LDS weight staging (GEMM pattern).
// WT: bf16 [300][1200] k-major = uint [300][600]. Chunk = 25 k rows (60 KB).
// 640 threads: 0..599 own gate-row pairs (2t,2t+1); 0..299 own unit t.
// ---------------------------------------------------------------------------
__global__ __launch_bounds__(640) void lstm_fast_k(
    const float* __restrict__ xW, const unsigned short* __restrict__ WT,
    const float* __restrict__ bih, const float* __restrict__ bhh,
    const int* __restrict__ lengths, float* __restrict__ encoded)
{
    __shared__ float hs[300];
    __shared__ float gs[1200];
    __shared__ __align__(16) unsigned wbuf[2][15000];   // 2 x 60 KB

    const int b = blockIdx.x, t = threadIdx.x;
    const int len = lengths[b];
    const bool ga = t < 600;
    const bool ha = t < 300;
    float bs0 = 0.f, bs1 = 0.f;
    if (ga) { bs0 = bih[2*t] + bhh[2*t]; bs1 = bih[2*t+1] + bhh[2*t+1]; }
    if (ha) hs[t] = 0.f;
    float c = 0.f, h = 0.f;
    const float* xb = xW + (size_t)b * Ll * 1200;
    const uint4* wsrc4 = (const uint4*)WT;   // chunk cc occupies [cc*3750, (cc+1)*3750)

    // stage chunk 0
    for (int i = t; i < 3750; i += 640) ((uint4*)wbuf[0])[i] = wsrc4[i];
    __syncthreads();

    int cur = 0;
    for (int st = 0; st < len; ++st) {
        float d0 = 0.f, d1 = 0.f, d2 = 0.f, d3 = 0.f;
        float xvx = 0.f, xvy = 0.f;
        if (ga) { float2 xv = *(const float2*)(xb + st * 1200 + 2 * t); xvx = xv.x; xvy = xv.y; }
        for (int cc = 0; cc < 12; ++cc) {
            // stage next chunk (wraps to chunk 0 for the next step)
            {
                int nxt = (cc + 1) % 12;
                const uint4* src = wsrc4 + nxt * 3750;
                uint4* dst = (uint4*)wbuf[cur ^ 1];
                for (int i = t; i < 3750; i += 640) dst[i] = src[i];
            }
            if (ga) {
                const unsigned* wb = &wbuf[cur][t];
                const int k0 = cc * 25;
                #pragma unroll
                for (int j = 0; j < 24; j += 2) {
                    float hk0 = hs[k0 + j], hk1 = hs[k0 + j + 1];
                    unsigned w0 = wb[j * 600], w1 = wb[(j + 1) * 600];
                    d0 = fmaf(hk0, bflo(w0), d0); d1 = fmaf(hk0, bfhi(w0), d1);
                    d2 = fmaf(hk1, bflo(w1), d2); d3 = fmaf(hk1, bfhi(w1), d3);
                }
                { float hk = hs[k0 + 24]; unsigned w = wb[24 * 600];
                  d0 = fmaf(hk, bflo(w), d0); d1 = fmaf(hk, bfhi(w), d1); }
                if (cc == 11) {
                    gs[2*t]   = xvx + bs0 + d0 + d2;
                    gs[2*t+1] = xvy + bs1 + d1 + d3;
                }
            }
            __syncthreads();
            if (cc == 11) {
                if (ha) {
                    float i_ = sigf(gs[t]);
                    float f_ = sigf(gs[300 + t]);
                    float g_ = tanhf(gs[600 + t]);
                    float o_ = sigf(gs[900 + t]);
                    c = f_ * c + i_ * g_;
                    h = o_ * tanhf(c);
                    hs[t] = h;
                }
                __syncthreads();
            }
            cur ^= 1;
        }
    }
    if (ha) encoded[b * 300 + t] = h;
}

// Persistent RNN decoder
__global__ __launch_bounds__(320) void rnn_all_k(
    const float* __restrict__ enc, const float* __restrict__ WihT,
    const float* __restrict__ WhhT,
    const float* __restrict__ bih, const float* __restrict__ bhh,
    float* __restrict__ hidden)
{
    __shared__ float es[304];
    __shared__ float hs[304];
    const int b = blockIdx.x, i = threadIdx.x;
    const bool act = i < 300;
    if (act) { es[i] = enc[b * 300 + i]; hs[i] = 0.f; }
    __syncthreads();
    float ex = 0.f;
    if (act) {
        #pragma unroll 16
        for (int k = 0; k < 300; k++)
            ex = fmaf(es[k], WihT[(size_t)k * 300 + i], ex);
        ex += bih[i] + bhh[i];
    }
    for (int it = 0; it < NI; it++) {
        __syncthreads();
        float d = 0.f;
        if (act) {
            #pragma unroll 16
            for (int k = 0; k < 300; k++)
                d = fmaf(hs[k], WhhT[(size_t)k * 300 + i], d);
        }
        float v = fmaxf(ex + d, 0.f);
        __syncthreads();
        if (act) { hs[i] = v; hidden[((size_t)b * NI + it) * 300 + i] = v; }
    }
}

__global__ __launch_bounds__(256) void scores_instr_k(
    const float* __restrict__ hidden, const float* __restrict__ tagged,
    const int* __restrict__ lengths, float* __restrict__ instr)
{
    __shared__ float sc[4][32];
    int wv = threadIdx.x >> 6;
    int wid = blockIdx.x * 4 + wv;
    int lane = threadIdx.x & 63;
    int b = wid / NI;
    const float* hr = hidden + (size_t)wid * Hh;
    float hv[5];
    #pragma unroll
    for (int p = 0; p < 5; p++){ int k = lane + p * 64; hv[p] = (k < Hh) ? hr[k] : 0.f; }
    int len = lengths[b];
    for (int l = 0; l < Ll; l++){
        const float* trw = tagged + ((size_t)b * Ll + l) * Hh;
        float s = 0.f;
        #pragma unroll
        for (int p = 0; p < 5; p++){ int k = lane + p * 64; if (k < Hh) s += hv[p] * trw[k]; }
        s = wave_sum(s);
        if (lane == 0) sc[wv][l] = s;
    }
    __syncthreads();
    float mx = -3.4e38f;
    for (int l = 0; l < len; l++) mx = fmaxf(mx, sc[wv][l]);
    float sum = 0.f;
    for (int l = 0; l < len; l++) sum += expf(sc[wv][l] - mx);
    float inv = 1.f / sum;
    float a[5] = {0.f,0.f,0.f,0.f,0.f};
    for (int l = 0; l < len; l++){
        float pl = expf(sc[wv][l] - mx) * inv;
        const float* trw = tagged + ((size_t)b * Ll + l) * Hh;
        #pragma unroll
        for (int p = 0; p < 5; p++){ int k = lane + p * 64; if (k < Hh) a[p] += pl * trw[k]; }
    }
    #pragma unroll
    for (int p = 0; p < 5; p++){ int k = lane + p * 64; if (k < Hh) instr[(size_t)wid * Hh + k] = a[p]; }
}

__global__ __launch_bounds__(256) void prop_softmax_all_k(
    const float* __restrict__ instr, const float* __restrict__ pemb,
    float* __restrict__ psim5, float* __restrict__ rsim5)
{
    int wid = blockIdx.x * 4 + (threadIdx.x >> 6);
    int lane = threadIdx.x & 63;
    const float* ir = instr + (size_t)wid * Hh;
    float iv[5];
    #pragma unroll
    for (int p = 0; p < 5; p++){ int k = lane + p * 64; iv[p] = (k < Hh) ? ir[k] : 0.f; }
    float e[9];
    #pragma unroll
    for (int j = 0; j < 9; j++){
        const float* pr = pemb + j * Hh;
        float s = 0.f;
        #pragma unroll
        for (int p = 0; p < 5; p++){ int k = lane + p * 64; if (k < Hh) s += iv[p] * pr[k]; }
        e[j] = wave_sum(s);
    }
    if (lane == 0){
        float mx = e[0];
        #pragma unroll
        for (int j = 1; j < 9; j++) mx = fmaxf(mx, e[j]);
        float sum = 0.f;
        #pragma unroll
        for (int j = 0; j < 9; j++){ e[j] = expf(e[j] - mx); sum += e[j]; }
        float inv = 1.f / sum;
        #pragma unroll
        for (int p = 0; p < 8; p++) psim5[wid * 8 + p] = e[p] * inv;
        rsim5[wid] = e[8] * inv;
    }
}

__global__ void iscale4_k(const float* __restrict__ instr,
                          const float* __restrict__ psim5, float* __restrict__ iscale4)
{
    int idx = blockIdx.x * 256 + threadIdx.x;
    if (idx >= 4 * Bb * 2400) return;
    int step = idx / (Bb * 2400);
    int r = idx - step * (Bb * 2400);
    int b = r / 2400; int k = r - b * 2400;
    int p = k / 300;  int h = k - p * 300;
    iscale4[idx] = instr[((size_t)b * NI + step) * Hh + h] * psim5[(b * NI + step) * 8 + p];
}

__global__ void edge_msg_k(const int* __restrict__ ei, const float* __restrict__ es,
                           const float* __restrict__ dist, float* __restrict__ msgdot)
{
    int e = blockIdx.x * 256 + threadIdx.x;
    if (e < Ee){
        int s = ei[e];
        int d = ei[Ee + e];
        atomicAdd(&msgdot[d], dist[s] * es[e]);
    }
}

// seg_update also re-zeros its msgdot range for the next iteration.
__global__ __launch_bounds__(256) void seg_update_k(
    const float* __restrict__ nscore, float* __restrict__ msgdot,
    const float* __restrict__ rsim5, int step, float* __restrict__ dist)
{
    int b = blockIdx.x, t = threadIdx.x;
    __shared__ float red[256];
    int n0 = b * NPG;
    float a1 = nscore[n0 + t], a2 = nscore[n0 + 256 + t];
    float m1 = msgdot[n0 + t], m2 = msgdot[n0 + 256 + t];

    red[t] = fmaxf(a1, a2); __syncthreads();
    for (int s = 128; s > 0; s >>= 1){ if (t < s) red[t] = fmaxf(red[t], red[t+s]); __syncthreads(); }
    float mN = red[0]; __syncthreads();
    float e1 = expf(a1 - mN), e2 = expf(a2 - mN);
    red[t] = e1 + e2; __syncthreads();
    for (int s = 128; s > 0; s >>= 1){ if (t < s) red[t] += red[t+s]; __syncthreads(); }
    float sN = red[0]; __syncthreads();

    red[t] = fmaxf(m1, m2); __syncthreads();
    for (int s = 128; s > 0; s >>= 1){ if (t < s) red[t] = fmaxf(red[t], red[t+s]); __syncthreads(); }
    float mM = red[0]; __syncthreads();
    float f1 = expf(m1 - mM), f2 = expf(m2 - mM);
    red[t] = f1 + f2; __syncthreads();
    for (int s = 128; s > 0; s >>= 1){ if (t < s) red[t] += red[t+s]; __syncthreads(); }
    float sM = red[0];

    float rs = rsim5[b * NI + step];
    dist[n0 + t]       = rs * (f1 / sM) + (1.f - rs) * (e1 / sN);
    dist[n0 + 256 + t] = rs * (f2 / sM) + (1.f - rs) * (e2 / sN);
    msgdot[n0 + t] = 0.f;
    msgdot[n0 + 256 + t] = 0.f;
}

// final aggregation (bf16 attrs)
__global__ __launch_bounds__(320) void final_agg_bf_k(
    const float* __restrict__ psim5, const float* __restrict__ dist,
    const unsigned short* __restrict__ nab, float* __restrict__ agg)
{
    int chunk = blockIdx.x;
    int b = blockIdx.y;
    int h = threadIdx.x;
    if (h >= Hh) return;
    float ps[8];
    #pragma unroll
    for (int p = 0; p < 8; p++) ps[p] = psim5[(b * NI + 4) * 8 + p];
    float acc = 0.f;
    for (int i = 0; i < 32; i++){
        int n = b * NPG + chunk * 32 + i;
        const unsigned short* row = nab + (size_t)n * 2400;
        float wsum = 0.f;
        #pragma unroll
        for (int p = 0; p < 8; p++) wsum += ps[p] * bf2f(row[p * Hh + h]);
        acc += dist[n] * wsum;
    }
    atomicAdd(&agg[b * Hh + h], acc);
}
__global__ __launch_bounds__(320) void final_agg_k(
    const float* __restrict__ psim5, const float* __restrict__ dist,
    const float* __restrict__ na, float* __restrict__ agg)
{
    int chunk = blockIdx.x;
    int b = blockIdx.y;
    int h = threadIdx.x;
    if (h >= Hh) return;
    float ps[8];
    #pragma unroll
    for (int p = 0; p < 8; p++) ps[p] = psim5[(b * NI + 4) * 8 + p];
    float acc = 0.f;
    for (int i = 0; i < 32; i++){
        int n = b * NPG + chunk * 32 + i;
        const float* row = na + (size_t)n * Pp * Hh;
        float wsum = 0.f;
        #pragma unroll
        for (int p = 0; p < 8; p++) wsum += ps[p] * row[p * Hh + h];
        acc += dist[n] * wsum;
    }
    atomicAdd(&agg[b * Hh + h], acc);
}

// fc1 with fused feats (reads enc | agg directly), elu epilogue
__global__ void fc1_k(const float* __restrict__ enc, const float* __restrict__ agg,
                      const float* __restrict__ W, const float* __restrict__ bias,
                      float* __restrict__ z)
{
    int idx = blockIdx.x * 256 + threadIdx.x;
    if (idx >= Bb * 600) return;
    int m = idx / 600, j = idx - m * 600;
    const float* wr = W + (size_t)j * 600;
    float s = 0.f;
    for (int k = 0; k < 300; k++) s += enc[m * 300 + k] * wr[k];
    for (int k = 0; k < 300; k++) s += agg[m * 300 + k] * wr[300 + k];
    z[idx] = eluf(s + bias[j]);
}

__global__ void fc2_k(const float* __restrict__ z, const float* __restrict__ W,
                      const float* __restrict__ bias, float* __restrict__ out)
{
    int idx = blockIdx.x * 256 + threadIdx.x;
    if (idx >= Bb * 1845) return;
    int m = idx / 1845, j = idx - m * 1845;
    const float* wr = W + (size_t)j * 600;
    const float* zr = z + m * 600;
    float s = 0.f;
    for (int k = 0; k < 600; k++) s += zr[k] * wr[k];
    out[idx] = s + bias[j];
}

// ---------------------------------------------------------------------------
extern "C" void kernel_launch(void* const* d_in, const int* in_sizes, int n_in,
                              void* d_out, int out_size, void* d_ws, size_t ws_size,
                              hipStream_t stream)
{
    const float* questions      = (const float*)d_in[0];
    const int*   lengths        = (const int*)  d_in[1];
    const int*   node_indices   = (const int*)  d_in[2];
    const int*   edge_indices   = (const int*)  d_in[3];
    const int*   edge_batch     = (const int*)  d_in[4];
    const float* node_attrs     = (const float*)d_in[5];
    const float* edge_attrs     = (const float*)d_in[6];
    const float* concept_vocab  = (const float*)d_in[7];
    const float* prop_emb       = (const float*)d_in[8];
    const float* tagger_default = (const float*)d_in[9];
    const float* tagger_weight  = (const float*)d_in[10];
    const float* lstm_Wih       = (const float*)d_in[11];
    const float* lstm_Whh       = (const float*)d_in[12];
    const float* lstm_bih       = (const float*)d_in[13];
    const float* lstm_bhh       = (const float*)d_in[14];
    const float* rnn_Wih        = (const float*)d_in[15];
    const float* rnn_Whh        = (const float*)d_in[16];
    const float* rnn_bih        = (const float*)d_in[17];
    const float* rnn_bhh        = (const float*)d_in[18];
    const float* Wnp            = (const float*)d_in[19];
    const float* Wedge          = (const float*)d_in[20];
    const float* w_nscore       = (const float*)d_in[21];
    const float* w_rscore       = (const float*)d_in[22];
    const float* fc1_W          = (const float*)d_in[23];
    const float* fc1_b          = (const float*)d_in[24];
    const float* fc2_W          = (const float*)d_in[25];
    const float* fc2_b          = (const float*)d_in[26];
    float* outf = (float*)d_out;

    float* ws = (float*)d_ws;
    size_t off = 0;
    auto alloc = [&](size_t n){ size_t r = off; off += (n + 63) & ~(size_t)63; return r; };
    size_t o_q2     = alloc(960 * 300);
    size_t o_sim    = alloc((size_t)960 * 2001);
    size_t o_tagged = alloc(960 * 300);
    size_t o_xw     = alloc((size_t)960 * 1200);
    size_t o_enc    = alloc(9600);
    size_t o_hidden = alloc(48000);
    size_t o_instr  = alloc(48000);
    size_t o_psim5  = alloc(1280);
    size_t o_rsim5  = alloc(160);
    size_t o_iscl4  = alloc((size_t)4 * Bb * 2400);
    size_t o_nsc4   = alloc((size_t)4 * Nn);
    size_t o_es4    = alloc((size_t)4 * Ee);
    size_t o_msgdot = alloc(Nn);
    size_t o_dist   = alloc(Nn);
    size_t o_agg    = alloc(9600);
    size_t o_z      = alloc(19200);
    size_t o_btn    = alloc((size_t)304 * 2400 / 2);
    size_t o_bte    = alloc((size_t)304 * 320 / 2);
    size_t o_wn     = alloc(304);
    size_t o_wr     = alloc(304);
    size_t o_wlstm  = alloc(180000);
    size_t o_rwhhT  = alloc(90000);
    size_t o_rwihT  = alloc(90000);
    size_t o_btq    = alloc((size_t)304 * 320 / 2);
    size_t o_btv    = alloc((size_t)2128 * 320 / 2);
    size_t o_btc    = alloc((size_t)304 * 2016 / 2);
    size_t o_btw    = alloc((size_t)1216 * 320 / 2);
    size_t o_nab    = alloc((size_t)Nn * 2400 / 2);
    size_t o_eab    = alloc((size_t)Ee * 320 / 2);
    const bool bigws = ws_size >= off * sizeof(float);

    unsigned short* btn = (unsigned short*)(ws + o_btn);
    unsigned short* bte = (unsigned short*)(ws + o_bte);
    unsigned short* wlstm = (unsigned short*)(ws + o_wlstm);
    unsigned short* btq = (unsigned short*)(ws + o_btq);
    unsigned short* btv = (unsigned short*)(ws + o_btv);
    unsigned short* btc = (unsigned short*)(ws + o_btc);
    unsigned short* btw = (unsigned short*)(ws + o_btw);
    unsigned short* nab = (unsigned short*)(ws + o_nab);
    unsigned short* eab = (unsigned short*)(ws + o_eab);

    // ---- one prep launch (all weight tables) + one convert launch ----
    prep_all_k<<<(R_TOTAL + 255)/256, 256, 0, stream>>>(
        Wnp, Wedge, tagger_weight, concept_vocab, tagger_default,
        lstm_Wih, lstm_Whh, rnn_Whh, rnn_Wih, w_nscore, w_rscore,
        btn, bte, btq, btv, btc, btw, wlstm,
        ws + o_rwhhT, ws + o_rwihT, ws + o_wn, ws + o_wr);
    if (bigws)
        cvt_both_k<<<2048, 256, 0, stream>>>(node_attrs, edge_attrs, nab, eab);

    // ---- tagger chain ----
    mfma_gemm_k<<<dim3(15,1), 256, 0, stream>>>(
        questions, 300, 300, 10, btq, 320, 300, ws + o_q2, 300, nullptr, nullptr);
    mfma_gemm_k<<<dim3(15,7), 256, 0, stream>>>(
        ws + o_q2, 300, 300, 10, btv, 320, 2001, ws + o_sim, 2001, nullptr, nullptr);
    softmax_rows_k<<<960, 256, 0, stream>>>(ws + o_sim, 2001);
    mfma_gemm_k<<<dim3(15,1), 256, 0, stream>>>(
        ws + o_sim, 2001, 2000, 63, btc, 2016, 300, ws + o_tagged, 300,
        ws + o_sim + 2000, questions);

    // ---- LSTM ----
    mfma_gemm_k<<<dim3(15,4), 256, 0, stream>>>(
        ws + o_tagged, 300, 300, 10, btw, 320, 1200, ws + o_xw, 1200, nullptr, nullptr);
    lstm_fast_k<<<Bb, 640, 0, stream>>>(ws + o_xw, wlstm, lstm_bih, lstm_bhh,
                                        lengths, ws + o_enc);

    // ---- RNN + instructions ----
    rnn_all_k<<<Bb, 320, 0, stream>>>(ws + o_enc, ws + o_rwihT, ws + o_rwhhT,
                                      rnn_bih, rnn_bhh, ws + o_hidden);
    scores_instr_k<<<40, 256, 0, stream>>>(ws + o_hidden, ws + o_tagged, lengths, ws + o_instr);

    // ---- hoisted data-parallel phase (batched over steps via blockIdx.y) ----
    prop_softmax_all_k<<<40, 256, 0, stream>>>(ws + o_instr, prop_emb, ws + o_psim5, ws + o_rsim5);
    iscale4_k<<<(4*Bb*2400 + 255)/256, 256, 0, stream>>>(ws + o_instr, ws + o_psim5, ws + o_iscl4);
    if (bigws) {
        mfma_node_k<<<dim3(Nn/64, 4), 256, 0, stream>>>(
            nab, btn, ws + o_iscl4, node_indices, ws + o_wn, ws + o_nsc4);
        mfma_edge_k<<<dim3(Ee/64, 4), 256, 0, stream>>>(
            eab, bte, ws + o_instr, edge_batch, ws + o_wr, ws + o_es4);
    } else {
        mfma_node_f_k<<<dim3(Nn/64, 4), 256, 0, stream>>>(
            node_attrs, btn, ws + o_iscl4, node_indices, ws + o_wn, ws + o_nsc4);
        mfma_edge_f_k<<<dim3(Ee/64, 4), 256, 0, stream>>>(
            edge_attrs, bte, ws + o_instr, edge_batch, ws + o_wr, ws + o_es4);
    }

    // ---- serial message-passing tail ----
    init_k<<<64, 256, 0, stream>>>(ws + o_dist, ws + o_msgdot, ws + o_agg);
    for (int step = 0; step < 4; step++){
        edge_msg_k<<<512, 256, 0, stream>>>(edge_indices, ws + o_es4 + (size_t)step * Ee,
                                            ws + o_dist, ws + o_msgdot);
        seg_update_k<<<32, 256, 0, stream>>>(ws + o_nsc4 + (size_t)step * Nn, ws + o_msgdot,
                                             ws + o_rsim5, step, ws + o_dist);
    }

    // ---- final aggregation + FCs ----
    if (bigws)
        final_agg_bf_k<<<dim3(16,32), 320, 0, stream>>>(ws + o_psim5, ws + o_dist, nab, ws + o_agg);
    else
        final_agg_k<<<dim3(16,32), 320, 0, stream>>>(ws + o_psim5, ws + o_dist, node_attrs, ws + o_agg);
    fc1_k<<<75, 256, 0, stream>>>(ws + o_enc, ws + o_agg, fc1_W, fc1_b, ws + o_z);
    fc2_k<<<(Bb*1845 + 255)/256, 256, 0, stream>>>(ws + o_z, fc2_W, fc2_b, outf);
}

// Round 14
// 1282.006 us; speedup vs baseline: 1.1861x; 1.1861x over previous
//
#include <hip/hip_runtime.h>
#include <hip/hip_bf16.h>
#include <math.h>

#define Bb   32
#define Ll   30
#define Hh   300
#define Pp   8
#define Nn   16384
#define Ee   131072
#define NPG  512
#define NI   5

typedef __attribute__((ext_vector_type(4))) float f32x4;
typedef __attribute__((ext_vector_type(8))) short s16x8;

__device__ __forceinline__ float eluf(float x){ return x > 0.f ? x : expm1f(x); }
__device__ __forceinline__ float sigf(float x){ return 1.f/(1.f+expf(-x)); }
__device__ __forceinline__ float wave_sum(float s){
    s += __shfl_xor(s, 32); s += __shfl_xor(s, 16); s += __shfl_xor(s, 8);
    s += __shfl_xor(s, 4);  s += __shfl_xor(s, 2);  s += __shfl_xor(s, 1);
    return s;
}
__device__ __forceinline__ unsigned short f2bf(float x){
    unsigned u = __float_as_uint(x);
    unsigned r = u + 0x7FFFu + ((u >> 16) & 1u);
    return (unsigned short)(r >> 16);
}
__device__ __forceinline__ float bf2f(unsigned short v){
    return __uint_as_float(((unsigned)v) << 16);
}

// ---------------------------------------------------------------------------
// A-tile fetch
// ---------------------------------------------------------------------------
template<int KK, bool BFA>
__device__ __forceinline__ void fetch_as(const float* __restrict__ arowf,
                                         const unsigned short* __restrict__ arowb,
                                         const float* __restrict__ srow,
                                         int k, float* a8, float* s8)
{
    if constexpr (BFA) {
        s16x8 av = *(const s16x8*)(arowb + k);
        float4 w0 = *(const float4*)(srow + k), w1 = *(const float4*)(srow + k + 4);
        s8[0]=w0.x; s8[1]=w0.y; s8[2]=w0.z; s8[3]=w0.w; s8[4]=w1.x; s8[5]=w1.y; s8[6]=w1.z; s8[7]=w1.w;
        #pragma unroll
        for (int j = 0; j < 8; j++) a8[j] = bf2f((unsigned short)av[j]);
    } else {
        if (k + 8 <= KK) {
            float4 v0 = *(const float4*)(arowf + k), v1 = *(const float4*)(arowf + k + 4);
            a8[0]=v0.x; a8[1]=v0.y; a8[2]=v0.z; a8[3]=v0.w; a8[4]=v1.x; a8[5]=v1.y; a8[6]=v1.z; a8[7]=v1.w;
            float4 w0 = *(const float4*)(srow + k), w1 = *(const float4*)(srow + k + 4);
            s8[0]=w0.x; s8[1]=w0.y; s8[2]=w0.z; s8[3]=w0.w; s8[4]=w1.x; s8[5]=w1.y; s8[6]=w1.z; s8[7]=w1.w;
        } else {
            #pragma unroll
            for (int j = 0; j < 8; j++){ int kk = k + j; a8[j] = (kk < KK) ? arowf[kk] : 0.f; s8[j] = (kk < KK) ? srow[kk] : 0.f; }
        }
    }
}

// ---------------------------------------------------------------------------
// MFMA scored-GEMM. Single-buffered Bs (35.5 KB LDS) -> 3 blocks/CU.
// 4 waves = 4 col quarters, 64 rows each.
// ---------------------------------------------------------------------------
template<int KK, int BPITCH, int NTILES, bool BFA>
__device__ __forceinline__ void mfma_score_impl(
    const float* __restrict__ Af, const unsigned short* __restrict__ Ab, int lda,
    const unsigned short* __restrict__ Bt,
    const float* __restrict__ S, int sstride, const int* __restrict__ rowb,
    const float* __restrict__ wpad,
    float* __restrict__ out)
{
    __shared__ unsigned short As[2][64*40];
    __shared__ unsigned short Bs[304*40];
    __shared__ float red[4][64];

    const int t = threadIdx.x;
    const int wc = t >> 6, lane = t & 63;
    const int l15 = lane & 15, g = lane >> 4;
    const int rowBlock = blockIdx.x * 64;

    const int sr = t >> 2;
    const int sk = (t & 3) * 8;
    const int grow = rowBlock + sr;
    const int bb = rowb[grow];
    const float* arowf = nullptr;
    const unsigned short* arowb = nullptr;
    if constexpr (BFA) arowb = Ab + (size_t)grow * lda;
    else               arowf = Af + (size_t)grow * lda;
    const float* srow = S + (size_t)bb * sstride;

    f32x4 acc[4][5];
    #pragma unroll
    for (int rt = 0; rt < 4; rt++)
        #pragma unroll
        for (int ct = 0; ct < 5; ct++) acc[rt][ct] = (f32x4){0.f,0.f,0.f,0.f};

    float a8[8], s8[8];
    s16x8 bvec[5];

    // prologue: stage tile 0
    {
        fetch_as<KK, BFA>(arowf, arowb, srow, sk, a8, s8);
        #pragma unroll
        for (int i = 0; i < 5; i++){
            int v = t + 256 * i;
            if (v < 1216) bvec[i] = *(const s16x8*)&Bt[(size_t)(v >> 2) * BPITCH + ((v & 3) * 8)];
        }
        s16x8 pv;
        #pragma unroll
        for (int j = 0; j < 8; j++) pv[j] = (short)f2bf(a8[j] * s8[j]);
        *(s16x8*)&As[0][sr * 40 + sk] = pv;
        #pragma unroll
        for (int i = 0; i < 5; i++){
            int v = t + 256 * i;
            if (v < 1216) *(s16x8*)&Bs[(v >> 2) * 40 + ((v & 3) * 8)] = bvec[i];
        }
    }
    __syncthreads();

    int cur = 0;
    for (int kt = 0; kt < NTILES; ++kt) {
        const bool has_next = (kt + 1 < NTILES);
        if (has_next) {
            fetch_as<KK, BFA>(arowf, arowb, srow, (kt + 1) * 32 + sk, a8, s8);
            int k0 = (kt + 1) * 32;
            #pragma unroll
            for (int i = 0; i < 5; i++){
                int v = t + 256 * i;
                if (v < 1216) bvec[i] = *(const s16x8*)&Bt[(size_t)(v >> 2) * BPITCH + k0 + ((v & 3) * 8)];
            }
        }
        s16x8 af[4];
        #pragma unroll
        for (int rt = 0; rt < 4; rt++)
            af[rt] = *(s16x8*)&As[cur][(rt * 16 + l15) * 40 + g * 8];
        #pragma unroll
        for (int ct = 0; ct < 5; ct++) {
            if (wc == 3 && ct == 4) continue;
            int col = wc * 80 + ct * 16 + l15;
            s16x8 bf = *(s16x8*)&Bs[col * 40 + g * 8];
            #pragma unroll
            for (int rt = 0; rt < 4; rt++)
                acc[rt][ct] = __builtin_amdgcn_mfma_f32_16x16x32_bf16(af[rt], bf, acc[rt][ct], 0, 0, 0);
        }
        if (has_next) {
            __syncthreads();                       // all reads of Bs done
            s16x8 pv;
            #pragma unroll
            for (int j = 0; j < 8; j++) pv[j] = (short)f2bf(a8[j] * s8[j]);
            *(s16x8*)&As[cur ^ 1][sr * 40 + sk] = pv;
            #pragma unroll
            for (int i = 0; i < 5; i++){
                int v = t + 256 * i;
                if (v < 1216) *(s16x8*)&Bs[(v >> 2) * 40 + ((v & 3) * 8)] = bvec[i];
            }
            __syncthreads();                       // next tile visible
            cur ^= 1;
        }
    }

    float p[4][4];
    #pragma unroll
    for (int rt = 0; rt < 4; rt++)
        #pragma unroll
        for (int i = 0; i < 4; i++) p[rt][i] = 0.f;
    #pragma unroll
    for (int ct = 0; ct < 5; ct++) {
        if (wc == 3 && ct == 4) continue;
        int col = wc * 80 + ct * 16 + l15;
        float wv = wpad[col];
        #pragma unroll
        for (int rt = 0; rt < 4; rt++)
            #pragma unroll
            for (int i = 0; i < 4; i++)
                p[rt][i] += eluf(acc[rt][ct][i]) * wv;
    }
    #pragma unroll
    for (int m = 1; m <= 8; m <<= 1) {
        #pragma unroll
        for (int rt = 0; rt < 4; rt++)
            #pragma unroll
            for (int i = 0; i < 4; i++)
                p[rt][i] += __shfl_xor(p[rt][i], m);
    }
    __syncthreads();                               // acc done; safe to reuse red
    if (l15 == 0) {
        #pragma unroll
        for (int rt = 0; rt < 4; rt++)
            #pragma unroll
            for (int i = 0; i < 4; i++)
                red[wc][rt * 16 + g * 4 + i] = p[rt][i];
    }
    __syncthreads();
    if (t < 64)
        out[rowBlock + t] = red[0][t] + red[1][t] + red[2][t] + red[3][t];
}

// Batched over steps: blockIdx.y = step (0..3)
__global__ __launch_bounds__(256, 3) void mfma_node_k(
    const unsigned short* __restrict__ Ab, const unsigned short* __restrict__ Bt,
    const float* __restrict__ iscl4, const int* __restrict__ rowb,
    const float* __restrict__ wpad, float* __restrict__ nsc4)
{
    const int step = blockIdx.y;
    mfma_score_impl<2400, 2400, 75, true>(nullptr, Ab, 2400, Bt,
        iscl4 + (size_t)step * Bb * 2400, 2400, rowb, wpad,
        nsc4 + (size_t)step * Nn);
}
__global__ __launch_bounds__(256, 3) void mfma_edge_k(
    const unsigned short* __restrict__ Ab, const unsigned short* __restrict__ Bt,
    const float* __restrict__ instr, const int* __restrict__ rowb,
    const float* __restrict__ wpad, float* __restrict__ es4)
{
    const int step = blockIdx.y;
    mfma_score_impl<320, 320, 10, true>(nullptr, Ab, 320, Bt,
        instr + step * 300, NI * 300, rowb, wpad,
        es4 + (size_t)step * Ee);
}
__global__ __launch_bounds__(256, 3) void mfma_node_f_k(
    const float* __restrict__ A, const unsigned short* __restrict__ Bt,
    const float* __restrict__ iscl4, const int* __restrict__ rowb,
    const float* __restrict__ wpad, float* __restrict__ nsc4)
{
    const int step = blockIdx.y;
    mfma_score_impl<2400, 2400, 75, false>(A, nullptr, 2400, Bt,
        iscl4 + (size_t)step * Bb * 2400, 2400, rowb, wpad,
        nsc4 + (size_t)step * Nn);
}
__global__ __launch_bounds__(256, 3) void mfma_edge_f_k(
    const float* __restrict__ A, const unsigned short* __restrict__ Bt,
    const float* __restrict__ instr, const int* __restrict__ rowb,
    const float* __restrict__ wpad, float* __restrict__ es4)
{
    const int step = blockIdx.y;
    mfma_score_impl<300, 320, 10, false>(A, nullptr, 300, Bt,
        instr + step * 300, NI * 300, rowb, wpad,
        es4 + (size_t)step * Ee);
}

// ---------------------------------------------------------------------------
// Generic MFMA GEMM (tagger chain; unchanged 2-buffer form).
// ---------------------------------------------------------------------------
__global__ __launch_bounds__(256, 2) void mfma_gemm_k(
    const float* __restrict__ A, int lda, int K, int ntiles,
    const unsigned short* __restrict__ Bt, int bpitch,
    int ncols, float* __restrict__ C, int ldc,
    const float* __restrict__ simlast, const float* __restrict__ qm)
{
    __shared__ unsigned short As[2][64*40];
    __shared__ unsigned short Bs[2][304*40];

    const int t = threadIdx.x;
    const int wc = t >> 6, lane = t & 63;
    const int l15 = lane & 15, g = lane >> 4;
    const int rowBlock = blockIdx.x * 64;
    const int colBlock = blockIdx.y * 304;

    const int sr = t >> 2, sk = (t & 3) * 8;
    const float* arow = A + (size_t)(rowBlock + sr) * lda;

    f32x4 acc[4][5];
    #pragma unroll
    for (int rt = 0; rt < 4; rt++)
        #pragma unroll
        for (int ct = 0; ct < 5; ct++) acc[rt][ct] = (f32x4){0.f,0.f,0.f,0.f};

    float a8[8];
    s16x8 bvec[5];

    {
        int k = sk;
        if (k + 8 <= K) {
            float4 v0 = *(const float4*)(arow + k), v1 = *(const float4*)(arow + k + 4);
            a8[0]=v0.x; a8[1]=v0.y; a8[2]=v0.z; a8[3]=v0.w; a8[4]=v1.x; a8[5]=v1.y; a8[6]=v1.z; a8[7]=v1.w;
        } else {
            #pragma unroll
            for (int j = 0; j < 8; j++){ int kk = k + j; a8[j] = (kk < K) ? arow[kk] : 0.f; }
        }
        #pragma unroll
        for (int i = 0; i < 5; i++){
            int v = t + 256 * i;
            if (v < 1216) bvec[i] = *(const s16x8*)&Bt[(size_t)(colBlock + (v >> 2)) * bpitch + ((v & 3) * 8)];
        }
        s16x8 pv;
        #pragma unroll
        for (int j = 0; j < 8; j++) pv[j] = (short)f2bf(a8[j]);
        *(s16x8*)&As[0][sr * 40 + sk] = pv;
        #pragma unroll
        for (int i = 0; i < 5; i++){
            int v = t + 256 * i;
            if (v < 1216) *(s16x8*)&Bs[0][(v >> 2) * 40 + ((v & 3) * 8)] = bvec[i];
        }
    }
    __syncthreads();

    int cur = 0;
    for (int kt = 0; kt < ntiles; ++kt) {
        if (kt + 1 < ntiles) {
            int k = (kt + 1) * 32 + sk;
            if (k + 8 <= K) {
                float4 v0 = *(const float4*)(arow + k), v1 = *(const float4*)(arow + k + 4);
                a8[0]=v0.x; a8[1]=v0.y; a8[2]=v0.z; a8[3]=v0.w; a8[4]=v1.x; a8[5]=v1.y; a8[6]=v1.z; a8[7]=v1.w;
            } else {
                #pragma unroll
                for (int j = 0; j < 8; j++){ int kk = k + j; a8[j] = (kk < K) ? arow[kk] : 0.f; }
            }
            int k0 = (kt + 1) * 32;
            #pragma unroll
            for (int i = 0; i < 5; i++){
                int v = t + 256 * i;
                if (v < 1216) bvec[i] = *(const s16x8*)&Bt[(size_t)(colBlock + (v >> 2)) * bpitch + k0 + ((v & 3) * 8)];
            }
        }
        s16x8 af[4];
        #pragma unroll
        for (int rt = 0; rt < 4; rt++)
            af[rt] = *(s16x8*)&As[cur][(rt * 16 + l15) * 40 + g * 8];
        #pragma unroll
        for (int ct = 0; ct < 5; ct++) {
            if (wc == 3 && ct == 4) continue;
            int col = wc * 80 + ct * 16 + l15;
            s16x8 bf = *(s16x8*)&Bs[cur][col * 40 + g * 8];
            #pragma unroll
            for (int rt = 0; rt < 4; rt++)
                acc[rt][ct] = __builtin_amdgcn_mfma_f32_16x16x32_bf16(af[rt], bf, acc[rt][ct], 0, 0, 0);
        }
        if (kt + 1 < ntiles) {
            s16x8 pv;
            #pragma unroll
            for (int j = 0; j < 8; j++) pv[j] = (short)f2bf(a8[j]);
            *(s16x8*)&As[cur ^ 1][sr * 40 + sk] = pv;
            #pragma unroll
            for (int i = 0; i < 5; i++){
                int v = t + 256 * i;
                if (v < 1216) *(s16x8*)&Bs[cur ^ 1][(v >> 2) * 40 + ((v & 3) * 8)] = bvec[i];
            }
        }
        __syncthreads();
        cur ^= 1;
    }

    #pragma unroll
    for (int ct = 0; ct < 5; ct++) {
        if (wc == 3 && ct == 4) continue;
        int col = colBlock + wc * 80 + ct * 16 + l15;
        if (col >= ncols) continue;
        #pragma unroll
        for (int rt = 0; rt < 4; rt++) {
            int row0 = rowBlock + rt * 16 + g * 4;
            #pragma unroll
            for (int i = 0; i < 4; i++) {
                float v = acc[rt][ct][i];
                int row = row0 + i;
                if (simlast) v += simlast[(size_t)row * 2001] * qm[(size_t)row * 300 + col];
                C[(size_t)row * ldc + col] = v;
            }
        }
    }
}

// ---------------------------------------------------------------------------
// ONE prep kernel: all weight-table builds (flat-index range dispatch).
// ---------------------------------------------------------------------------
#define R_BTN   729600
#define R_BTE   (R_BTN + 97280)
#define R_BTQ   (R_BTE + 97280)
#define R_BTV   (R_BTQ + 680960)
#define R_BTC   (R_BTV + 612864)
#define R_BTW   (R_BTC + 389120)
#define R_WL    (R_BTW + 360000)
#define R_RWH   (R_WL + 90000)
#define R_RWI   (R_RWH + 90000)
#define R_WP    (R_RWI + 608)
#define R_TOTAL R_WP

__global__ void prep_all_k(
    const float* __restrict__ Wnp, const float* __restrict__ Wedge,
    const float* __restrict__ tagger_weight, const float* __restrict__ cv,
    const float* __restrict__ td, const float* __restrict__ lstm_Wih,
    const float* __restrict__ lstm_Whh, const float* __restrict__ rnn_Whh,
    const float* __restrict__ rnn_Wih, const float* __restrict__ wn,
    const float* __restrict__ wr,
    unsigned short* __restrict__ btn, unsigned short* __restrict__ bte,
    unsigned short* __restrict__ btq, unsigned short* __restrict__ btv,
    unsigned short* __restrict__ btc, unsigned short* __restrict__ btw,
    unsigned short* __restrict__ wlstm, float* __restrict__ rwhhT,
    float* __restrict__ rwihT, float* __restrict__ wnp, float* __restrict__ wrp)
{
    int idx = blockIdx.x * 256 + threadIdx.x;
    if (idx >= R_TOTAL) return;
    if (idx < R_BTN) {
        int col = idx / 2400, k = idx - col * 2400;
        btn[idx] = f2bf((col < 300) ? Wnp[(size_t)k * 300 + col] : 0.f);
    } else if (idx < R_BTE) {
        int r = idx - R_BTN;
        int col = r / 320, k = r - col * 320;
        bte[r] = f2bf((col < 300 && k < 300) ? Wedge[(size_t)k * 300 + col] : 0.f);
    } else if (idx < R_BTQ) {
        int r = idx - R_BTE;
        int col = r / 320, k = r - col * 320;
        btq[r] = f2bf((col < 300 && k < 300) ? tagger_weight[(size_t)k * 300 + col] : 0.f);
    } else if (idx < R_BTV) {
        int r = idx - R_BTQ;
        int col = r / 320, k = r - col * 320;
        float v = 0.f;
        if (k < 300) {
            if (col < 2000) v = cv[(size_t)col * 300 + k];
            else if (col == 2000) v = td[k];
        }
        btv[r] = f2bf(v);
    } else if (idx < R_BTC) {
        int r = idx - R_BTV;
        int col = r / 2016, k = r - col * 2016;
        btc[r] = f2bf((col < 300 && k < 2000) ? cv[(size_t)k * 300 + col] : 0.f);
    } else if (idx < R_BTW) {
        int r = idx - R_BTC;
        int col = r / 320, k = r - col * 320;
        btw[r] = f2bf((col < 1200 && k < 300) ? lstm_Wih[(size_t)col * 300 + k] : 0.f);
    } else if (idx < R_WL) {
        int r = idx - R_BTW;
        int k = r / 1200, row = r - k * 1200;
        wlstm[r] = f2bf(lstm_Whh[(size_t)row * 300 + k]);
    } else if (idx < R_RWH) {
        int r = idx - R_WL;
        int row = r / 300, c = r - row * 300;
        rwhhT[(size_t)c * 300 + row] = rnn_Whh[r];
    } else if (idx < R_RWI) {
        int r = idx - R_RWH;
        int row = r / 300, c = r - row * 300;
        rwihT[(size_t)c * 300 + row] = rnn_Wih[r];
    } else {
        int r = idx - R_RWI;
        if (r < 304) wnp[r] = (r < 300) ? wn[r] : 0.f;
        else { int r2 = r - 304; wrp[r2] = (r2 < 300) ? wr[r2] : 0.f; }
    }
}

// ONE convert kernel for both attr arrays
__global__ void cvt_both_k(const float* __restrict__ na, const float* __restrict__ ea,
                           unsigned short* __restrict__ nab, unsigned short* __restrict__ eab)
{
    const long NG = (long)Nn * 300;
    const long EG = (long)Ee * 40;
    const long total = NG + EG;
    for (long i = (long)blockIdx.x * blockDim.x + threadIdx.x; i < total;
         i += (long)gridDim.x * blockDim.x) {
        if (i < NG) {
            long base = i * 8;
            float4 v0 = *(const float4*)(na + base);
            float4 v1 = *(const float4*)(na + base + 4);
            s16x8 v;
            v[0]=(short)f2bf(v0.x); v[1]=(short)f2bf(v0.y); v[2]=(short)f2bf(v0.z); v[3]=(short)f2bf(v0.w);
            v[4]=(short)f2bf(v1.x); v[5]=(short)f2bf(v1.y); v[6]=(short)f2bf(v1.z); v[7]=(short)f2bf(v1.w);
            *(s16x8*)&nab[base] = v;
        } else {
            long r2 = i - NG;
            long row = r2 / 40;
            int kg = (int)(r2 - row * 40) * 8;
            s16x8 v;
            #pragma unroll
            for (int j = 0; j < 8; j++){
                int k = kg + j;
                float x = (k < 300) ? ea[row * 300 + k] : 0.f;
                v[j] = (short)f2bf(x);
            }
            *(s16x8*)&eab[row * 320 + kg] = v;
        }
    }
}

// dist = 1/512, msgdot = 0, agg = 0 (one launch)
__global__ void init_k(float* __restrict__ dist, float* __restrict__ msgdot,
                       float* __restrict__ agg)
{
    int n = blockIdx.x * 256 + threadIdx.x;
    if (n < Nn) { dist[n] = 1.f / (float)NPG; msgdot[n] = 0.f; }
    if (n < 9600) agg[n] = 0.f;
}

// ---------------------------------------------------------------------------
__global__ void softmax_rows_k(float* __restrict__ X, int nc)
{
    int row = blockIdx.x, t = threadIdx.x;
    __shared__ float red[256];
    size_t base = (size_t)row * nc;
    float m = -3.4e38f;
    for (int i = t; i < nc; i += 256) m = fmaxf(m, X[base + i]);
    red[t] = m; __syncthreads();
    for (int s = 128; s > 0; s >>= 1){ if (t < s) red[t] = fmaxf(red[t], red[t+s]); __syncthreads(); }
    float mx = red[0]; __syncthreads();
    float sm = 0.f;
    for (int i = t; i < nc; i += 256){ float e = expf(X[base + i] - mx); X[base + i] = e; sm += e; }
    red[t] = sm; __syncthreads();
    for (int s = 128; s > 0; s >>= 1){ if (t < s) red[t] += red[t+s]; __syncthreads(); }
    float inv = 1.f / red[0];
    for (int i = t; i < nc; i += 256) X[base + i] *= inv;
}

// Fast persistent LSTM (round-8/12 measured-good: seq access, 4 accumulators)
__global__ __launch_bounds__(640) void lstm_fast_k(
    const float* __restrict__ xW, const unsigned short* __restrict__ WT,
    const float* __restrict__ bih, const float* __restrict__ bhh,
    const int* __restrict__ lengths, float* __restrict__ encoded)
{
    __shared__ float hs[300];
    __shared__ float gs[1200];
    const int b = blockIdx.x, t = threadIdx.x;
    const int len = lengths[b];
    const bool ga = t < 600;
    const bool ha = t < 300;
    float bs0 = 0.f, bs1 = 0.f;
    if (ga) { bs0 = bih[2*t] + bhh[2*t]; bs1 = bih[2*t+1] + bhh[2*t+1]; }
    if (ha) hs[t] = 0.f;
    float c = 0.f, h = 0.f;
    __syncthreads();
    const float* xb = xW + (size_t)b * Ll * 1200;
    for (int st = 0; st < len; ++st) {
        if (ga) {
            float2 xv = *(const float2*)(xb + st * 1200 + 2 * t);
            float d0 = 0.f, d1 = 0.f, d2 = 0.f, d3 = 0.f;
            const unsigned short* wp = WT + 2 * t;
            #pragma unroll 8
            for (int k = 0; k < 300; k += 2) {
                float hk0 = hs[k], hk1 = hs[k + 1];
                unsigned wv0 = *(const unsigned*)(wp + (size_t)k * 1200);
                unsigned wv1 = *(const unsigned*)(wp + (size_t)(k + 1) * 1200);
                d0 = fmaf(hk0, __uint_as_float(wv0 << 16), d0);
                d1 = fmaf(hk0, __uint_as_float(wv0 & 0xFFFF0000u), d1);
                d2 = fmaf(hk1, __uint_as_float(wv1 << 16), d2);
                d3 = fmaf(hk1, __uint_as_float(wv1 & 0xFFFF0000u), d3);
            }
            gs[2*t]   = xv.x + bs0 + d0 + d2;
            gs[2*t+1] = xv.y + bs1 + d1 + d3;
        }
        __syncthreads();
        if (ha) {
            float i_ = sigf(gs[t]);
            float f_ = sigf(gs[300 + t]);
            float g_ = tanhf(gs[600 + t]);
            float o_ = sigf(gs[900 + t]);
            c = f_ * c + i_ * g_;
            h = o_ * tanhf(c);
            hs[t] = h;
        }
        __syncthreads();
    }
    if (ha) encoded[b * 300 + t] = h;
}

// Persistent RNN decoder
__global__ __launch_bounds__(320) void rnn_all_k(
    const float* __restrict__ enc, const float* __restrict__ WihT,
    const float* __restrict__ WhhT,
    const float* __restrict__ bih, const float* __restrict__ bhh,
    float* __restrict__ hidden)
{
    __shared__ float es[304];
    __shared__ float hs[304];
    const int b = blockIdx.x, i = threadIdx.x;
    const bool act = i < 300;
    if (act) { es[i] = enc[b * 300 + i]; hs[i] = 0.f; }
    __syncthreads();
    float ex = 0.f;
    if (act) {
        #pragma unroll 8
        for (int k = 0; k < 300; k++)
            ex = fmaf(es[k], WihT[(size_t)k * 300 + i], ex);
        ex += bih[i] + bhh[i];
    }
    for (int it = 0; it < NI; it++) {
        __syncthreads();
        float d = 0.f;
        if (act) {
            #pragma unroll 8
            for (int k = 0; k < 300; k++)
                d = fmaf(hs[k], WhhT[(size_t)k * 300 + i], d);
        }
        float v = fmaxf(ex + d, 0.f);
        __syncthreads();
        if (act) { hs[i] = v; hidden[((size_t)b * NI + it) * 300 + i] = v; }
    }
}

__global__ __launch_bounds__(256) void scores_instr_k(
    const float* __restrict__ hidden, const float* __restrict__ tagged,
    const int* __restrict__ lengths, float* __restrict__ instr)
{
    __shared__ float sc[4][32];
    int wv = threadIdx.x >> 6;
    int wid = blockIdx.x * 4 + wv;
    int lane = threadIdx.x & 63;
    int b = wid / NI;
    const float* hr = hidden + (size_t)wid * Hh;
    float hv[5];
    #pragma unroll
    for (int p = 0; p < 5; p++){ int k = lane + p * 64; hv[p] = (k < Hh) ? hr[k] : 0.f; }
    int len = lengths[b];
    for (int l = 0; l < Ll; l++){
        const float* trw = tagged + ((size_t)b * Ll + l) * Hh;
        float s = 0.f;
        #pragma unroll
        for (int p = 0; p < 5; p++){ int k = lane + p * 64; if (k < Hh) s += hv[p] * trw[k]; }
        s = wave_sum(s);
        if (lane == 0) sc[wv][l] = s;
    }
    __syncthreads();
    float mx = -3.4e38f;
    for (int l = 0; l < len; l++) mx = fmaxf(mx, sc[wv][l]);
    float sum = 0.f;
    for (int l = 0; l < len; l++) sum += expf(sc[wv][l] - mx);
    float inv = 1.f / sum;
    float a[5] = {0.f,0.f,0.f,0.f,0.f};
    for (int l = 0; l < len; l++){
        float pl = expf(sc[wv][l] - mx) * inv;
        const float* trw = tagged + ((size_t)b * Ll + l) * Hh;
        #pragma unroll
        for (int p = 0; p < 5; p++){ int k = lane + p * 64; if (k < Hh) a[p] += pl * trw[k]; }
    }
    #pragma unroll
    for (int p = 0; p < 5; p++){ int k = lane + p * 64; if (k < Hh) instr[(size_t)wid * Hh + k] = a[p]; }
}

__global__ __launch_bounds__(256) void prop_softmax_all_k(
    const float* __restrict__ instr, const float* __restrict__ pemb,
    float* __restrict__ psim5, float* __restrict__ rsim5)
{
    int wid = blockIdx.x * 4 + (threadIdx.x >> 6);
    int lane = threadIdx.x & 63;
    const float* ir = instr + (size_t)wid * Hh;
    float iv[5];
    #pragma unroll
    for (int p = 0; p < 5; p++){ int k = lane + p * 64; iv[p] = (k < Hh) ? ir[k] : 0.f; }
    float e[9];
    #pragma unroll
    for (int j = 0; j < 9; j++){
        const float* pr = pemb + j * Hh;
        float s = 0.f;
        #pragma unroll
        for (int p = 0; p < 5; p++){ int k = lane + p * 64; if (k < Hh) s += iv[p] * pr[k]; }
        e[j] = wave_sum(s);
    }
    if (lane == 0){
        float mx = e[0];
        #pragma unroll
        for (int j = 1; j < 9; j++) mx = fmaxf(mx, e[j]);
        float sum = 0.f;
        #pragma unroll
        for (int j = 0; j < 9; j++){ e[j] = expf(e[j] - mx); sum += e[j]; }
        float inv = 1.f / sum;
        #pragma unroll
        for (int p = 0; p < 8; p++) psim5[wid * 8 + p] = e[p] * inv;
        rsim5[wid] = e[8] * inv;
    }
}

__global__ void iscale4_k(const float* __restrict__ instr,
                          const float* __restrict__ psim5, float* __restrict__ iscale4)
{
    int idx = blockIdx.x * 256 + threadIdx.x;
    if (idx >= 4 * Bb * 2400) return;
    int step = idx / (Bb * 2400);
    int r = idx - step * (Bb * 2400);
    int b = r / 2400; int k = r - b * 2400;
    int p = k / 300;  int h = k - p * 300;
    iscale4[idx] = instr[((size_t)b * NI + step) * Hh + h] * psim5[(b * NI + step) * 8 + p];
}

__global__ void edge_msg_k(const int* __restrict__ ei, const float* __restrict__ es,
                           const float* __restrict__ dist, float* __restrict__ msgdot)
{
    int e = blockIdx.x * 256 + threadIdx.x;
    if (e < Ee){
        int s = ei[e];
        int d = ei[Ee + e];
        atomicAdd(&msgdot[d], dist[s] * es[e]);
    }
}

// seg_update also re-zeros its msgdot range for the next iteration.
__global__ __launch_bounds__(256) void seg_update_k(
    const float* __restrict__ nscore, float* __restrict__ msgdot,
    const float* __restrict__ rsim5, int step, float* __restrict__ dist)
{
    int b = blockIdx.x, t = threadIdx.x;
    __shared__ float red[256];
    int n0 = b * NPG;
    float a1 = nscore[n0 + t], a2 = nscore[n0 + 256 + t];
    float m1 = msgdot[n0 + t], m2 = msgdot[n0 + 256 + t];

    red[t] = fmaxf(a1, a2); __syncthreads();
    for (int s = 128; s > 0; s >>= 1){ if (t < s) red[t] = fmaxf(red[t], red[t+s]); __syncthreads(); }
    float mN = red[0]; __syncthreads();
    float e1 = expf(a1 - mN), e2 = expf(a2 - mN);
    red[t] = e1 + e2; __syncthreads();
    for (int s = 128; s > 0; s >>= 1){ if (t < s) red[t] += red[t+s]; __syncthreads(); }
    float sN = red[0]; __syncthreads();

    red[t] = fmaxf(m1, m2); __syncthreads();
    for (int s = 128; s > 0; s >>= 1){ if (t < s) red[t] = fmaxf(red[t], red[t+s]); __syncthreads(); }
    float mM = red[0]; __syncthreads();
    float f1 = expf(m1 - mM), f2 = expf(m2 - mM);
    red[t] = f1 + f2; __syncthreads();
    for (int s = 128; s > 0; s >>= 1){ if (t < s) red[t] += red[t+s]; __syncthreads(); }
    float sM = red[0];

    float rs = rsim5[b * NI + step];
    dist[n0 + t]       = rs * (f1 / sM) + (1.f - rs) * (e1 / sN);
    dist[n0 + 256 + t] = rs * (f2 / sM) + (1.f - rs) * (e2 / sN);
    msgdot[n0 + t] = 0.f;
    msgdot[n0 + 256 + t] = 0.f;
}

// final aggregation (bf16 attrs)
__global__ __launch_bounds__(320) void final_agg_bf_k(
    const float* __restrict__ psim5, const float* __restrict__ dist,
    const unsigned short* __restrict__ nab, float* __restrict__ agg)
{
    int chunk = blockIdx.x;
    int b = blockIdx.y;
    int h = threadIdx.x;
    if (h >= Hh) return;
    float ps[8];
    #pragma unroll
    for (int p = 0; p < 8; p++) ps[p] = psim5[(b * NI + 4) * 8 + p];
    float acc = 0.f;
    for (int i = 0; i < 32; i++){
        int n = b * NPG + chunk * 32 + i;
        const unsigned short* row = nab + (size_t)n * 2400;
        float wsum = 0.f;
        #pragma unroll
        for (int p = 0; p < 8; p++) wsum += ps[p] * bf2f(row[p * Hh + h]);
        acc += dist[n] * wsum;
    }
    atomicAdd(&agg[b * Hh + h], acc);
}
__global__ __launch_bounds__(320) void final_agg_k(
    const float* __restrict__ psim5, const float* __restrict__ dist,
    const float* __restrict__ na, float* __restrict__ agg)
{
    int chunk = blockIdx.x;
    int b = blockIdx.y;
    int h = threadIdx.x;
    if (h >= Hh) return;
    float ps[8];
    #pragma unroll
    for (int p = 0; p < 8; p++) ps[p] = psim5[(b * NI + 4) * 8 + p];
    float acc = 0.f;
    for (int i = 0; i < 32; i++){
        int n = b * NPG + chunk * 32 + i;
        const float* row = na + (size_t)n * Pp * Hh;
        float wsum = 0.f;
        #pragma unroll
        for (int p = 0; p < 8; p++) wsum += ps[p] * row[p * Hh + h];
        acc += dist[n] * wsum;
    }
    atomicAdd(&agg[b * Hh + h], acc);
}

// fc1 with fused feats (reads enc | agg directly), elu epilogue
__global__ void fc1_k(const float* __restrict__ enc, const float* __restrict__ agg,
                      const float* __restrict__ W, const float* __restrict__ bias,
                      float* __restrict__ z)
{
    int idx = blockIdx.x * 256 + threadIdx.x;
    if (idx >= Bb * 600) return;
    int m = idx / 600, j = idx - m * 600;
    const float* wr = W + (size_t)j * 600;
    float s = 0.f;
    for (int k = 0; k < 300; k++) s += enc[m * 300 + k] * wr[k];
    for (int k = 0; k < 300; k++) s += agg[m * 300 + k] * wr[300 + k];
    z[idx] = eluf(s + bias[j]);
}

__global__ void fc2_k(const float* __restrict__ z, const float* __restrict__ W,
                      const float* __restrict__ bias, float* __restrict__ out)
{
    int idx = blockIdx.x * 256 + threadIdx.x;
    if (idx >= Bb * 1845) return;
    int m = idx / 1845, j = idx - m * 1845;
    const float* wr = W + (size_t)j * 600;
    const float* zr = z + m * 600;
    float s = 0.f;
    for (int k = 0; k < 600; k++) s += zr[k] * wr[k];
    out[idx] = s + bias[j];
}

// ---------------------------------------------------------------------------
extern "C" void kernel_launch(void* const* d_in, const int* in_sizes, int n_in,
                              void* d_out, int out_size, void* d_ws, size_t ws_size,
                              hipStream_t stream)
{
    const float* questions      = (const float*)d_in[0];
    const int*   lengths        = (const int*)  d_in[1];
    const int*   node_indices   = (const int*)  d_in[2];
    const int*   edge_indices   = (const int*)  d_in[3];
    const int*   edge_batch     = (const int*)  d_in[4];
    const float* node_attrs     = (const float*)d_in[5];
    const float* edge_attrs     = (const float*)d_in[6];
    const float* concept_vocab  = (const float*)d_in[7];
    const float* prop_emb       = (const float*)d_in[8];
    const float* tagger_default = (const float*)d_in[9];
    const float* tagger_weight  = (const float*)d_in[10];
    const float* lstm_Wih       = (const float*)d_in[11];
    const float* lstm_Whh       = (const float*)d_in[12];
    const float* lstm_bih       = (const float*)d_in[13];
    const float* lstm_bhh       = (const float*)d_in[14];
    const float* rnn_Wih        = (const float*)d_in[15];
    const float* rnn_Whh        = (const float*)d_in[16];
    const float* rnn_bih        = (const float*)d_in[17];
    const float* rnn_bhh        = (const float*)d_in[18];
    const float* Wnp            = (const float*)d_in[19];
    const float* Wedge          = (const float*)d_in[20];
    const float* w_nscore       = (const float*)d_in[21];
    const float* w_rscore       = (const float*)d_in[22];
    const float* fc1_W          = (const float*)d_in[23];
    const float* fc1_b          = (const float*)d_in[24];
    const float* fc2_W          = (const float*)d_in[25];
    const float* fc2_b          = (const float*)d_in[26];
    float* outf = (float*)d_out;

    float* ws = (float*)d_ws;
    size_t off = 0;
    auto alloc = [&](size_t n){ size_t r = off; off += (n + 63) & ~(size_t)63; return r; };
    size_t o_q2     = alloc(960 * 300);
    size_t o_sim    = alloc((size_t)960 * 2001);
    size_t o_tagged = alloc(960 * 300);
    size_t o_xw     = alloc((size_t)960 * 1200);
    size_t o_enc    = alloc(9600);
    size_t o_hidden = alloc(48000);
    size_t o_instr  = alloc(48000);
    size_t o_psim5  = alloc(1280);
    size_t o_rsim5  = alloc(160);
    size_t o_iscl4  = alloc((size_t)4 * Bb * 2400);
    size_t o_nsc4   = alloc((size_t)4 * Nn);
    size_t o_es4    = alloc((size_t)4 * Ee);
    size_t o_msgdot = alloc(Nn);
    size_t o_dist   = alloc(Nn);
    size_t o_agg    = alloc(9600);
    size_t o_z      = alloc(19200);
    size_t o_btn    = alloc((size_t)304 * 2400 / 2);
    size_t o_bte    = alloc((size_t)304 * 320 / 2);
    size_t o_wn     = alloc(304);
    size_t o_wr     = alloc(304);
    size_t o_wlstm  = alloc(180000);
    size_t o_rwhhT  = alloc(90000);
    size_t o_rwihT  = alloc(90000);
    size_t o_btq    = alloc((size_t)304 * 320 / 2);
    size_t o_btv    = alloc((size_t)2128 * 320 / 2);
    size_t o_btc    = alloc((size_t)304 * 2016 / 2);
    size_t o_btw    = alloc((size_t)1216 * 320 / 2);
    size_t o_nab    = alloc((size_t)Nn * 2400 / 2);
    size_t o_eab    = alloc((size_t)Ee * 320 / 2);
    const bool bigws = ws_size >= off * sizeof(float);

    unsigned short* btn = (unsigned short*)(ws + o_btn);
    unsigned short* bte = (unsigned short*)(ws + o_bte);
    unsigned short* wlstm = (unsigned short*)(ws + o_wlstm);
    unsigned short* btq = (unsigned short*)(ws + o_btq);
    unsigned short* btv = (unsigned short*)(ws + o_btv);
    unsigned short* btc = (unsigned short*)(ws + o_btc);
    unsigned short* btw = (unsigned short*)(ws + o_btw);
    unsigned short* nab = (unsigned short*)(ws + o_nab);
    unsigned short* eab = (unsigned short*)(ws + o_eab);

    // ---- one prep launch (all weight tables) + one convert launch ----
    prep_all_k<<<(R_TOTAL + 255)/256, 256, 0, stream>>>(
        Wnp, Wedge, tagger_weight, concept_vocab, tagger_default,
        lstm_Wih, lstm_Whh, rnn_Whh, rnn_Wih, w_nscore, w_rscore,
        btn, bte, btq, btv, btc, btw, wlstm,
        ws + o_rwhhT, ws + o_rwihT, ws + o_wn, ws + o_wr);
    if (bigws)
        cvt_both_k<<<2048, 256, 0, stream>>>(node_attrs, edge_attrs, nab, eab);

    // ---- tagger chain ----
    mfma_gemm_k<<<dim3(15,1), 256, 0, stream>>>(
        questions, 300, 300, 10, btq, 320, 300, ws + o_q2, 300, nullptr, nullptr);
    mfma_gemm_k<<<dim3(15,7), 256, 0, stream>>>(
        ws + o_q2, 300, 300, 10, btv, 320, 2001, ws + o_sim, 2001, nullptr, nullptr);
    softmax_rows_k<<<960, 256, 0, stream>>>(ws + o_sim, 2001);
    mfma_gemm_k<<<dim3(15,1), 256, 0, stream>>>(
        ws + o_sim, 2001, 2000, 63, btc, 2016, 300, ws + o_tagged, 300,
        ws + o_sim + 2000, questions);

    // ---- LSTM ----
    mfma_gemm_k<<<dim3(15,4), 256, 0, stream>>>(
        ws + o_tagged, 300, 300, 10, btw, 320, 1200, ws + o_xw, 1200, nullptr, nullptr);
    lstm_fast_k<<<Bb, 640, 0, stream>>>(ws + o_xw, wlstm, lstm_bih, lstm_bhh,
                                        lengths, ws + o_enc);

    // ---- RNN + instructions ----
    rnn_all_k<<<Bb, 320, 0, stream>>>(ws + o_enc, ws + o_rwihT, ws + o_rwhhT,
                                      rnn_bih, rnn_bhh, ws + o_hidden);
    scores_instr_k<<<40, 256, 0, stream>>>(ws + o_hidden, ws + o_tagged, lengths, ws + o_instr);

    // ---- hoisted data-parallel phase (batched over steps via blockIdx.y) ----
    prop_softmax_all_k<<<40, 256, 0, stream>>>(ws + o_instr, prop_emb, ws + o_psim5, ws + o_rsim5);
    iscale4_k<<<(4*Bb*2400 + 255)/256, 256, 0, stream>>>(ws + o_instr, ws + o_psim5, ws + o_iscl4);
    if (bigws) {
        mfma_node_k<<<dim3(Nn/64, 4), 256, 0, stream>>>(
            nab, btn, ws + o_iscl4, node_indices, ws + o_wn, ws + o_nsc4);
        mfma_edge_k<<<dim3(Ee/64, 4), 256, 0, stream>>>(
            eab, bte, ws + o_instr, edge_batch, ws + o_wr, ws + o_es4);
    } else {
        mfma_node_f_k<<<dim3(Nn/64, 4), 256, 0, stream>>>(
            node_attrs, btn, ws + o_iscl4, node_indices, ws + o_wn, ws + o_nsc4);
        mfma_edge_f_k<<<dim3(Ee/64, 4), 256, 0, stream>>>(
            edge_attrs, bte, ws + o_instr, edge_batch, ws + o_wr, ws + o_es4);
    }

    // ---- serial message-passing tail ----
    init_k<<<64, 256, 0, stream>>>(ws + o_dist, ws + o_msgdot, ws + o_agg);
    for (int step = 0; step < 4; step++){
        edge_msg_k<<<512, 256, 0, stream>>>(edge_indices, ws + o_es4 + (size_t)step * Ee,
                                            ws + o_dist, ws + o_msgdot);
        seg_update_k<<<32, 256, 0, stream>>>(ws + o_nsc4 + (size_t)step * Nn, ws + o_msgdot,
                                             ws + o_rsim5, step, ws + o_dist);
    }

    // ---- final aggregation + FCs ----
    if (bigws)
        final_agg_bf_k<<<dim3(16,32), 320, 0, stream>>>(ws + o_psim5, ws + o_dist, nab, ws + o_agg);
    else
        final_agg_k<<<dim3(16,32), 320, 0, stream>>>(ws + o_psim5, ws + o_dist, node_attrs, ws + o_agg);
    fc1_k<<<75, 256, 0, stream>>>(ws + o_enc, ws + o_agg, fc1_W, fc1_b, ws + o_z);
    fc2_k<<<(Bb*1845 + 255)/256, 256, 0, stream>>>(ws + o_z, fc2_W, fc2_b, outf);
}

// Round 16
// 1279.836 us; speedup vs baseline: 1.1881x; 1.0017x over previous
//
#include <hip/hip_runtime.h>
#include <hip/hip_bf16.h>
#include <math.h>

#define Bb   32
#define Ll   30
#define Hh   300
#define Pp   8
#define Nn   16384
#define Ee   131072
#define NPG  512
#define NI   5

typedef __attribute__((ext_vector_type(4))) float f32x4;
typedef __attribute__((ext_vector_type(8))) short s16x8;

__device__ __forceinline__ float eluf(float x){ return x > 0.f ? x : expm1f(x); }
__device__ __forceinline__ float sigf(float x){ return 1.f/(1.f+expf(-x)); }
__device__ __forceinline__ float wave_sum(float s){
    s += __shfl_xor(s, 32); s += __shfl_xor(s, 16); s += __shfl_xor(s, 8);
    s += __shfl_xor(s, 4);  s += __shfl_xor(s, 2);  s += __shfl_xor(s, 1);
    return s;
}
__device__ __forceinline__ unsigned short f2bf(float x){
    unsigned u = __float_as_uint(x);
    unsigned r = u + 0x7FFFu + ((u >> 16) & 1u);
    return (unsigned short)(r >> 16);
}
__device__ __forceinline__ float bf2f(unsigned short v){
    return __uint_as_float(((unsigned)v) << 16);
}

// ---------------------------------------------------------------------------
// A-tile fetch
// ---------------------------------------------------------------------------
template<int KK, bool BFA>
__device__ __forceinline__ void fetch_as(const float* __restrict__ arowf,
                                         const unsigned short* __restrict__ arowb,
                                         const float* __restrict__ srow,
                                         int k, float* a8, float* s8)
{
    if constexpr (BFA) {
        s16x8 av = *(const s16x8*)(arowb + k);
        float4 w0 = *(const float4*)(srow + k), w1 = *(const float4*)(srow + k + 4);
        s8[0]=w0.x; s8[1]=w0.y; s8[2]=w0.z; s8[3]=w0.w; s8[4]=w1.x; s8[5]=w1.y; s8[6]=w1.z; s8[7]=w1.w;
        #pragma unroll
        for (int j = 0; j < 8; j++) a8[j] = bf2f((unsigned short)av[j]);
    } else {
        if (k + 8 <= KK) {
            float4 v0 = *(const float4*)(arowf + k), v1 = *(const float4*)(arowf + k + 4);
            a8[0]=v0.x; a8[1]=v0.y; a8[2]=v0.z; a8[3]=v0.w; a8[4]=v1.x; a8[5]=v1.y; a8[6]=v1.z; a8[7]=v1.w;
            float4 w0 = *(const float4*)(srow + k), w1 = *(const float4*)(srow + k + 4);
            s8[0]=w0.x; s8[1]=w0.y; s8[2]=w0.z; s8[3]=w0.w; s8[4]=w1.x; s8[5]=w1.y; s8[6]=w1.z; s8[7]=w1.w;
        } else {
            #pragma unroll
            for (int j = 0; j < 8; j++){ int kk = k + j; a8[j] = (kk < KK) ? arowf[kk] : 0.f; s8[j] = (kk < KK) ? srow[kk] : 0.f; }
        }
    }
}

// ---------------------------------------------------------------------------
// MFMA scored-GEMM. Single-buffered Bs (35.5 KB LDS) -> 3 blocks/CU.
// ---------------------------------------------------------------------------
template<int KK, int BPITCH, int NTILES, bool BFA>
__device__ __forceinline__ void mfma_score_impl(
    const float* __restrict__ Af, const unsigned short* __restrict__ Ab, int lda,
    const unsigned short* __restrict__ Bt,
    const float* __restrict__ S, int sstride, const int* __restrict__ rowb,
    const float* __restrict__ wpad,
    float* __restrict__ out)
{
    __shared__ unsigned short As[2][64*40];
    __shared__ unsigned short Bs[304*40];
    __shared__ float red[4][64];

    const int t = threadIdx.x;
    const int wc = t >> 6, lane = t & 63;
    const int l15 = lane & 15, g = lane >> 4;
    const int rowBlock = blockIdx.x * 64;

    const int sr = t >> 2;
    const int sk = (t & 3) * 8;
    const int grow = rowBlock + sr;
    const int bb = rowb[grow];
    const float* arowf = nullptr;
    const unsigned short* arowb = nullptr;
    if constexpr (BFA) arowb = Ab + (size_t)grow * lda;
    else               arowf = Af + (size_t)grow * lda;
    const float* srow = S + (size_t)bb * sstride;

    f32x4 acc[4][5];
    #pragma unroll
    for (int rt = 0; rt < 4; rt++)
        #pragma unroll
        for (int ct = 0; ct < 5; ct++) acc[rt][ct] = (f32x4){0.f,0.f,0.f,0.f};

    float a8[8], s8[8];
    s16x8 bvec[5];

    {
        fetch_as<KK, BFA>(arowf, arowb, srow, sk, a8, s8);
        #pragma unroll
        for (int i = 0; i < 5; i++){
            int v = t + 256 * i;
            if (v < 1216) bvec[i] = *(const s16x8*)&Bt[(size_t)(v >> 2) * BPITCH + ((v & 3) * 8)];
        }
        s16x8 pv;
        #pragma unroll
        for (int j = 0; j < 8; j++) pv[j] = (short)f2bf(a8[j] * s8[j]);
        *(s16x8*)&As[0][sr * 40 + sk] = pv;
        #pragma unroll
        for (int i = 0; i < 5; i++){
            int v = t + 256 * i;
            if (v < 1216) *(s16x8*)&Bs[(v >> 2) * 40 + ((v & 3) * 8)] = bvec[i];
        }
    }
    __syncthreads();

    int cur = 0;
    for (int kt = 0; kt < NTILES; ++kt) {
        const bool has_next = (kt + 1 < NTILES);
        if (has_next) {
            fetch_as<KK, BFA>(arowf, arowb, srow, (kt + 1) * 32 + sk, a8, s8);
            int k0 = (kt + 1) * 32;
            #pragma unroll
            for (int i = 0; i < 5; i++){
                int v = t + 256 * i;
                if (v < 1216) bvec[i] = *(const s16x8*)&Bt[(size_t)(v >> 2) * BPITCH + k0 + ((v & 3) * 8)];
            }
        }
        s16x8 af[4];
        #pragma unroll
        for (int rt = 0; rt < 4; rt++)
            af[rt] = *(s16x8*)&As[cur][(rt * 16 + l15) * 40 + g * 8];
        #pragma unroll
        for (int ct = 0; ct < 5; ct++) {
            if (wc == 3 && ct == 4) continue;
            int col = wc * 80 + ct * 16 + l15;
            s16x8 bf = *(s16x8*)&Bs[col * 40 + g * 8];
            #pragma unroll
            for (int rt = 0; rt < 4; rt++)
                acc[rt][ct] = __builtin_amdgcn_mfma_f32_16x16x32_bf16(af[rt], bf, acc[rt][ct], 0, 0, 0);
        }
        if (has_next) {
            __syncthreads();
            s16x8 pv;
            #pragma unroll
            for (int j = 0; j < 8; j++) pv[j] = (short)f2bf(a8[j] * s8[j]);
            *(s16x8*)&As[cur ^ 1][sr * 40 + sk] = pv;
            #pragma unroll
            for (int i = 0; i < 5; i++){
                int v = t + 256 * i;
                if (v < 1216) *(s16x8*)&Bs[(v >> 2) * 40 + ((v & 3) * 8)] = bvec[i];
            }
            __syncthreads();
            cur ^= 1;
        }
    }

    float p[4][4];
    #pragma unroll
    for (int rt = 0; rt < 4; rt++)
        #pragma unroll
        for (int i = 0; i < 4; i++) p[rt][i] = 0.f;
    #pragma unroll
    for (int ct = 0; ct < 5; ct++) {
        if (wc == 3 && ct == 4) continue;
        int col = wc * 80 + ct * 16 + l15;
        float wv = wpad[col];
        #pragma unroll
        for (int rt = 0; rt < 4; rt++)
            #pragma unroll
            for (int i = 0; i < 4; i++)
                p[rt][i] += eluf(acc[rt][ct][i]) * wv;
    }
    #pragma unroll
    for (int m = 1; m <= 8; m <<= 1) {
        #pragma unroll
        for (int rt = 0; rt < 4; rt++)
            #pragma unroll
            for (int i = 0; i < 4; i++)
                p[rt][i] += __shfl_xor(p[rt][i], m);
    }
    __syncthreads();
    if (l15 == 0) {
        #pragma unroll
        for (int rt = 0; rt < 4; rt++)
            #pragma unroll
            for (int i = 0; i < 4; i++)
                red[wc][rt * 16 + g * 4 + i] = p[rt][i];
    }
    __syncthreads();
    if (t < 64)
        out[rowBlock + t] = red[0][t] + red[1][t] + red[2][t] + red[3][t];
}

// Batched over steps: blockIdx.y = step (0..3)
__global__ __launch_bounds__(256, 3) void mfma_node_k(
    const unsigned short* __restrict__ Ab, const unsigned short* __restrict__ Bt,
    const float* __restrict__ iscl4, const int* __restrict__ rowb,
    const float* __restrict__ wpad, float* __restrict__ nsc4)
{
    const int step = blockIdx.y;
    mfma_score_impl<2400, 2400, 75, true>(nullptr, Ab, 2400, Bt,
        iscl4 + (size_t)step * Bb * 2400, 2400, rowb, wpad,
        nsc4 + (size_t)step * Nn);
}
__global__ __launch_bounds__(256, 3) void mfma_edge_k(
    const unsigned short* __restrict__ Ab, const unsigned short* __restrict__ Bt,
    const float* __restrict__ instr, const int* __restrict__ rowb,
    const float* __restrict__ wpad, float* __restrict__ es4)
{
    const int step = blockIdx.y;
    mfma_score_impl<320, 320, 10, true>(nullptr, Ab, 320, Bt,
        instr + step * 300, NI * 300, rowb, wpad,
        es4 + (size_t)step * Ee);
}
__global__ __launch_bounds__(256, 3) void mfma_node_f_k(
    const float* __restrict__ A, const unsigned short* __restrict__ Bt,
    const float* __restrict__ iscl4, const int* __restrict__ rowb,
    const float* __restrict__ wpad, float* __restrict__ nsc4)
{
    const int step = blockIdx.y;
    mfma_score_impl<2400, 2400, 75, false>(A, nullptr, 2400, Bt,
        iscl4 + (size_t)step * Bb * 2400, 2400, rowb, wpad,
        nsc4 + (size_t)step * Nn);
}
__global__ __launch_bounds__(256, 3) void mfma_edge_f_k(
    const float* __restrict__ A, const unsigned short* __restrict__ Bt,
    const float* __restrict__ instr, const int* __restrict__ rowb,
    const float* __restrict__ wpad, float* __restrict__ es4)
{
    const int step = blockIdx.y;
    mfma_score_impl<300, 320, 10, false>(A, nullptr, 300, Bt,
        instr + step * 300, NI * 300, rowb, wpad,
        es4 + (size_t)step * Ee);
}

// ---------------------------------------------------------------------------
// Generic MFMA GEMM (tagger chain; 2-buffer form).
// ---------------------------------------------------------------------------
__global__ __launch_bounds__(256, 2) void mfma_gemm_k(
    const float* __restrict__ A, int lda, int K, int ntiles,
    const unsigned short* __restrict__ Bt, int bpitch,
    int ncols, float* __restrict__ C, int ldc,
    const float* __restrict__ simlast, const float* __restrict__ qm)
{
    __shared__ unsigned short As[2][64*40];
    __shared__ unsigned short Bs[2][304*40];

    const int t = threadIdx.x;
    const int wc = t >> 6, lane = t & 63;
    const int l15 = lane & 15, g = lane >> 4;
    const int rowBlock = blockIdx.x * 64;
    const int colBlock = blockIdx.y * 304;

    const int sr = t >> 2, sk = (t & 3) * 8;
    const float* arow = A + (size_t)(rowBlock + sr) * lda;

    f32x4 acc[4][5];
    #pragma unroll
    for (int rt = 0; rt < 4; rt++)
        #pragma unroll
        for (int ct = 0; ct < 5; ct++) acc[rt][ct] = (f32x4){0.f,0.f,0.f,0.f};

    float a8[8];
    s16x8 bvec[5];

    {
        int k = sk;
        if (k + 8 <= K) {
            float4 v0 = *(const float4*)(arow + k), v1 = *(const float4*)(arow + k + 4);
            a8[0]=v0.x; a8[1]=v0.y; a8[2]=v0.z; a8[3]=v0.w; a8[4]=v1.x; a8[5]=v1.y; a8[6]=v1.z; a8[7]=v1.w;
        } else {
            #pragma unroll
            for (int j = 0; j < 8; j++){ int kk = k + j; a8[j] = (kk < K) ? arow[kk] : 0.f; }
        }
        #pragma unroll
        for (int i = 0; i < 5; i++){
            int v = t + 256 * i;
            if (v < 1216) bvec[i] = *(const s16x8*)&Bt[(size_t)(colBlock + (v >> 2)) * bpitch + ((v & 3) * 8)];
        }
        s16x8 pv;
        #pragma unroll
        for (int j = 0; j < 8; j++) pv[j] = (short)f2bf(a8[j]);
        *(s16x8*)&As[0][sr * 40 + sk] = pv;
        #pragma unroll
        for (int i = 0; i < 5; i++){
            int v = t + 256 * i;
            if (v < 1216) *(s16x8*)&Bs[0][(v >> 2) * 40 + ((v & 3) * 8)] = bvec[i];
        }
    }
    __syncthreads();

    int cur = 0;
    for (int kt = 0; kt < ntiles; ++kt) {
        if (kt + 1 < ntiles) {
            int k = (kt + 1) * 32 + sk;
            if (k + 8 <= K) {
                float4 v0 = *(const float4*)(arow + k), v1 = *(const float4*)(arow + k + 4);
                a8[0]=v0.x; a8[1]=v0.y; a8[2]=v0.z; a8[3]=v0.w; a8[4]=v1.x; a8[5]=v1.y; a8[6]=v1.z; a8[7]=v1.w;
            } else {
                #pragma unroll
                for (int j = 0; j < 8; j++){ int kk = k + j; a8[j] = (kk < K) ? arow[kk] : 0.f; }
            }
            int k0 = (kt + 1) * 32;
            #pragma unroll
            for (int i = 0; i < 5; i++){
                int v = t + 256 * i;
                if (v < 1216) bvec[i] = *(const s16x8*)&Bt[(size_t)(colBlock + (v >> 2)) * bpitch + k0 + ((v & 3) * 8)];
            }
        }
        s16x8 af[4];
        #pragma unroll
        for (int rt = 0; rt < 4; rt++)
            af[rt] = *(s16x8*)&As[cur][(rt * 16 + l15) * 40 + g * 8];
        #pragma unroll
        for (int ct = 0; ct < 5; ct++) {
            if (wc == 3 && ct == 4) continue;
            int col = wc * 80 + ct * 16 + l15;
            s16x8 bf = *(s16x8*)&Bs[cur][col * 40 + g * 8];
            #pragma unroll
            for (int rt = 0; rt < 4; rt++)
                acc[rt][ct] = __builtin_amdgcn_mfma_f32_16x16x32_bf16(af[rt], bf, acc[rt][ct], 0, 0, 0);
        }
        if (kt + 1 < ntiles) {
            s16x8 pv;
            #pragma unroll
            for (int j = 0; j < 8; j++) pv[j] = (short)f2bf(a8[j]);
            *(s16x8*)&As[cur ^ 1][sr * 40 + sk] = pv;
            #pragma unroll
            for (int i = 0; i < 5; i++){
                int v = t + 256 * i;
                if (v < 1216) *(s16x8*)&Bs[cur ^ 1][(v >> 2) * 40 + ((v & 3) * 8)] = bvec[i];
            }
        }
        __syncthreads();
        cur ^= 1;
    }

    #pragma unroll
    for (int ct = 0; ct < 5; ct++) {
        if (wc == 3 && ct == 4) continue;
        int col = colBlock + wc * 80 + ct * 16 + l15;
        if (col >= ncols) continue;
        #pragma unroll
        for (int rt = 0; rt < 4; rt++) {
            int row0 = rowBlock + rt * 16 + g * 4;
            #pragma unroll
            for (int i = 0; i < 4; i++) {
                float v = acc[rt][ct][i];
                int row = row0 + i;
                if (simlast) v += simlast[(size_t)row * 2001] * qm[(size_t)row * 300 + col];
                C[(size_t)row * ldc + col] = v;
            }
        }
    }
}

// ---------------------------------------------------------------------------
// ONE prep kernel: all weight-table builds.
// ---------------------------------------------------------------------------
#define R_BTN   729600
#define R_BTE   (R_BTN + 97280)
#define R_BTQ   (R_BTE + 97280)
#define R_BTV   (R_BTQ + 680960)
#define R_BTC   (R_BTV + 612864)
#define R_BTW   (R_BTC + 389120)
#define R_WL    (R_BTW + 360000)
#define R_RWH   (R_WL + 90000)
#define R_RWI   (R_RWH + 90000)
#define R_WP    (R_RWI + 608)
#define R_TOTAL R_WP

__global__ void prep_all_k(
    const float* __restrict__ Wnp, const float* __restrict__ Wedge,
    const float* __restrict__ tagger_weight, const float* __restrict__ cv,
    const float* __restrict__ td, const float* __restrict__ lstm_Wih,
    const float* __restrict__ lstm_Whh, const float* __restrict__ rnn_Whh,
    const float* __restrict__ rnn_Wih, const float* __restrict__ wn,
    const float* __restrict__ wr,
    unsigned short* __restrict__ btn, unsigned short* __restrict__ bte,
    unsigned short* __restrict__ btq, unsigned short* __restrict__ btv,
    unsigned short* __restrict__ btc, unsigned short* __restrict__ btw,
    unsigned short* __restrict__ wlstm, float* __restrict__ rwhhT,
    float* __restrict__ rwihT, float* __restrict__ wnp, float* __restrict__ wrp)
{
    int idx = blockIdx.x * 256 + threadIdx.x;
    if (idx >= R_TOTAL) return;
    if (idx < R_BTN) {
        int col = idx / 2400, k = idx - col * 2400;
        btn[idx] = f2bf((col < 300) ? Wnp[(size_t)k * 300 + col] : 0.f);
    } else if (idx < R_BTE) {
        int r = idx - R_BTN;
        int col = r / 320, k = r - col * 320;
        bte[r] = f2bf((col < 300 && k < 300) ? Wedge[(size_t)k * 300 + col] : 0.f);
    } else if (idx < R_BTQ) {
        int r = idx - R_BTE;
        int col = r / 320, k = r - col * 320;
        btq[r] = f2bf((col < 300 && k < 300) ? tagger_weight[(size_t)k * 300 + col] : 0.f);
    } else if (idx < R_BTV) {
        int r = idx - R_BTQ;
        int col = r / 320, k = r - col * 320;
        float v = 0.f;
        if (k < 300) {
            if (col < 2000) v = cv[(size_t)col * 300 + k];
            else if (col == 2000) v = td[k];
        }
        btv[r] = f2bf(v);
    } else if (idx < R_BTC) {
        int r = idx - R_BTV;
        int col = r / 2016, k = r - col * 2016;
        btc[r] = f2bf((col < 300 && k < 2000) ? cv[(size_t)k * 300 + col] : 0.f);
    } else if (idx < R_BTW) {
        int r = idx - R_BTC;
        int col = r / 320, k = r - col * 320;
        btw[r] = f2bf((col < 1200 && k < 300) ? lstm_Wih[(size_t)col * 300 + k] : 0.f);
    } else if (idx < R_WL) {
        int r = idx - R_BTW;
        int k = r / 1200, row = r - k * 1200;
        wlstm[r] = f2bf(lstm_Whh[(size_t)row * 300 + k]);
    } else if (idx < R_RWH) {
        int r = idx - R_WL;
        int row = r / 300, c = r - row * 300;
        rwhhT[(size_t)c * 300 + row] = rnn_Whh[r];
    } else if (idx < R_RWI) {
        int r = idx - R_RWH;
        int row = r / 300, c = r - row * 300;
        rwihT[(size_t)c * 300 + row] = rnn_Wih[r];
    } else {
        int r = idx - R_RWI;
        if (r < 304) wnp[r] = (r < 300) ? wn[r] : 0.f;
        else { int r2 = r - 304; wrp[r2] = (r2 < 300) ? wr[r2] : 0.f; }
    }
}

// ONE convert kernel for both attr arrays
__global__ void cvt_both_k(const float* __restrict__ na, const float* __restrict__ ea,
                           unsigned short* __restrict__ nab, unsigned short* __restrict__ eab)
{
    const long NG = (long)Nn * 300;
    const long EG = (long)Ee * 40;
    const long total = NG + EG;
    for (long i = (long)blockIdx.x * blockDim.x + threadIdx.x; i < total;
         i += (long)gridDim.x * blockDim.x) {
        if (i < NG) {
            long base = i * 8;
            float4 v0 = *(const float4*)(na + base);
            float4 v1 = *(const float4*)(na + base + 4);
            s16x8 v;
            v[0]=(short)f2bf(v0.x); v[1]=(short)f2bf(v0.y); v[2]=(short)f2bf(v0.z); v[3]=(short)f2bf(v0.w);
            v[4]=(short)f2bf(v1.x); v[5]=(short)f2bf(v1.y); v[6]=(short)f2bf(v1.z); v[7]=(short)f2bf(v1.w);
            *(s16x8*)&nab[base] = v;
        } else {
            long r2 = i - NG;
            long row = r2 / 40;
            int kg = (int)(r2 - row * 40) * 8;
            s16x8 v;
            #pragma unroll
            for (int j = 0; j < 8; j++){
                int k = kg + j;
                float x = (k < 300) ? ea[row * 300 + k] : 0.f;
                v[j] = (short)f2bf(x);
            }
            *(s16x8*)&eab[row * 320 + kg] = v;
        }
    }
}

// ---------------------------------------------------------------------------
__global__ void softmax_rows_k(float* __restrict__ X, int nc)
{
    int row = blockIdx.x, t = threadIdx.x;
    __shared__ float red[256];
    size_t base = (size_t)row * nc;
    float m = -3.4e38f;
    for (int i = t; i < nc; i += 256) m = fmaxf(m, X[base + i]);
    red[t] = m; __syncthreads();
    for (int s = 128; s > 0; s >>= 1){ if (t < s) red[t] = fmaxf(red[t], red[t+s]); __syncthreads(); }
    float mx = red[0]; __syncthreads();
    float sm = 0.f;
    for (int i = t; i < nc; i += 256){ float e = expf(X[base + i] - mx); X[base + i] = e; sm += e; }
    red[t] = sm; __syncthreads();
    for (int s = 128; s > 0; s >>= 1){ if (t < s) red[t] += red[t+s]; __syncthreads(); }
    float inv = 1.f / red[0];
    for (int i = t; i < nc; i += 256) X[base + i] *= inv;
}

// Fast persistent LSTM (round-8/14 measured-good: 640 thr, seq access, 4 accums)
__global__ __launch_bounds__(640) void lstm_fast_k(
    const float* __restrict__ xW, const unsigned short* __restrict__ WT,
    const float* __restrict__ bih, const float* __restrict__ bhh,
    const int* __restrict__ lengths, float* __restrict__ encoded)
{
    __shared__ float hs[300];
    __shared__ float gs[1200];
    const int b = blockIdx.x, t = threadIdx.x;
    const int len = lengths[b];
    const bool ga = t < 600;
    const bool ha = t < 300;
    float bs0 = 0.f, bs1 = 0.f;
    if (ga) { bs0 = bih[2*t] + bhh[2*t]; bs1 = bih[2*t+1] + bhh[2*t+1]; }
    if (ha) hs[t] = 0.f;
    float c = 0.f, h = 0.f;
    __syncthreads();
    const float* xb = xW + (size_t)b * Ll * 1200;
    for (int st = 0; st < len; ++st) {
        if (ga) {
            float2 xv = *(const float2*)(xb + st * 1200 + 2 * t);
            float d0 = 0.f, d1 = 0.f, d2 = 0.f, d3 = 0.f;
            const unsigned short* wp = WT + 2 * t;
            #pragma unroll 8
            for (int k = 0; k < 300; k += 2) {
                float hk0 = hs[k], hk1 = hs[k + 1];
                unsigned wv0 = *(const unsigned*)(wp + (size_t)k * 1200);
                unsigned wv1 = *(const unsigned*)(wp + (size_t)(k + 1) * 1200);
                d0 = fmaf(hk0, __uint_as_float(wv0 << 16), d0);
                d1 = fmaf(hk0, __uint_as_float(wv0 & 0xFFFF0000u), d1);
                d2 = fmaf(hk1, __uint_as_float(wv1 << 16), d2);
                d3 = fmaf(hk1, __uint_as_float(wv1 & 0xFFFF0000u), d3);
            }
            gs[2*t]   = xv.x + bs0 + d0 + d2;
            gs[2*t+1] = xv.y + bs1 + d1 + d3;
        }
        __syncthreads();
        if (ha) {
            float i_ = sigf(gs[t]);
            float f_ = sigf(gs[300 + t]);
            float g_ = tanhf(gs[600 + t]);
            float o_ = sigf(gs[900 + t]);
            c = f_ * c + i_ * g_;
            h = o_ * tanhf(c);
            hs[t] = h;
        }
        __syncthreads();
    }
    if (ha) encoded[b * 300 + t] = h;
}

// Persistent RNN decoder
__global__ __launch_bounds__(320) void rnn_all_k(
    const float* __restrict__ enc, const float* __restrict__ WihT,
    const float* __restrict__ WhhT,
    const float* __restrict__ bih, const float* __restrict__ bhh,
    float* __restrict__ hidden)
{
    __shared__ float es[304];
    __shared__ float hs[304];
    const int b = blockIdx.x, i = threadIdx.x;
    const bool act = i < 300;
    if (act) { es[i] = enc[b * 300 + i]; hs[i] = 0.f; }
    __syncthreads();
    float ex = 0.f;
    if (act) {
        #pragma unroll 8
        for (int k = 0; k < 300; k++)
            ex = fmaf(es[k], WihT[(size_t)k * 300 + i], ex);
        ex += bih[i] + bhh[i];
    }
    for (int it = 0; it < NI; it++) {
        __syncthreads();
        float d = 0.f;
        if (act) {
            #pragma unroll 8
            for (int k = 0; k < 300; k++)
                d = fmaf(hs[k], WhhT[(size_t)k * 300 + i], d);
        }
        float v = fmaxf(ex + d, 0.f);
        __syncthreads();
        if (act) { hs[i] = v; hidden[((size_t)b * NI + it) * 300 + i] = v; }
    }
}

__global__ __launch_bounds__(256) void scores_instr_k(
    const float* __restrict__ hidden, const float* __restrict__ tagged,
    const int* __restrict__ lengths, float* __restrict__ instr)
{
    __shared__ float sc[4][32];
    int wv = threadIdx.x >> 6;
    int wid = blockIdx.x * 4 + wv;
    int lane = threadIdx.x & 63;
    int b = wid / NI;
    const float* hr = hidden + (size_t)wid * Hh;
    float hv[5];
    #pragma unroll
    for (int p = 0; p < 5; p++){ int k = lane + p * 64; hv[p] = (k < Hh) ? hr[k] : 0.f; }
    int len = lengths[b];
    for (int l = 0; l < Ll; l++){
        const float* trw = tagged + ((size_t)b * Ll + l) * Hh;
        float s = 0.f;
        #pragma unroll
        for (int p = 0; p < 5; p++){ int k = lane + p * 64; if (k < Hh) s += hv[p] * trw[k]; }
        s = wave_sum(s);
        if (lane == 0) sc[wv][l] = s;
    }
    __syncthreads();
    float mx = -3.4e38f;
    for (int l = 0; l < len; l++) mx = fmaxf(mx, sc[wv][l]);
    float sum = 0.f;
    for (int l = 0; l < len; l++) sum += expf(sc[wv][l] - mx);
    float inv = 1.f / sum;
    float a[5] = {0.f,0.f,0.f,0.f,0.f};
    for (int l = 0; l < len; l++){
        float pl = expf(sc[wv][l] - mx) * inv;
        const float* trw = tagged + ((size_t)b * Ll + l) * Hh;
        #pragma unroll
        for (int p = 0; p < 5; p++){ int k = lane + p * 64; if (k < Hh) a[p] += pl * trw[k]; }
    }
    #pragma unroll
    for (int p = 0; p < 5; p++){ int k = lane + p * 64; if (k < Hh) instr[(size_t)wid * Hh + k] = a[p]; }
}

__global__ __launch_bounds__(256) void prop_softmax_all_k(
    const float* __restrict__ instr, const float* __restrict__ pemb,
    float* __restrict__ psim5, float* __restrict__ rsim5)
{
    int wid = blockIdx.x * 4 + (threadIdx.x >> 6);
    int lane = threadIdx.x & 63;
    const float* ir = instr + (size_t)wid * Hh;
    float iv[5];
    #pragma unroll
    for (int p = 0; p < 5; p++){ int k = lane + p * 64; iv[p] = (k < Hh) ? ir[k] : 0.f; }
    float e[9];
    #pragma unroll
    for (int j = 0; j < 9; j++){
        const float* pr = pemb + j * Hh;
        float s = 0.f;
        #pragma unroll
        for (int p = 0; p < 5; p++){ int k = lane + p * 64; if (k < Hh) s += iv[p] * pr[k]; }
        e[j] = wave_sum(s);
    }
    if (lane == 0){
        float mx = e[0];
        #pragma unroll
        for (int j = 1; j < 9; j++) mx = fmaxf(mx, e[j]);
        float sum = 0.f;
        #pragma unroll
        for (int j = 0; j < 9; j++){ e[j] = expf(e[j] - mx); sum += e[j]; }
        float inv = 1.f / sum;
        #pragma unroll
        for (int p = 0; p < 8; p++) psim5[wid * 8 + p] = e[p] * inv;
        rsim5[wid] = e[8] * inv;
    }
}

// iscale4 + fused init (dist/msgdot/agg)
__global__ void iscale4_k(const float* __restrict__ instr,
                          const float* __restrict__ psim5, float* __restrict__ iscale4,
                          float* __restrict__ dist, float* __restrict__ msgdot,
                          float* __restrict__ agg)
{
    int idx = blockIdx.x * 256 + threadIdx.x;
    if (idx < Nn) { dist[idx] = 1.f / (float)NPG; msgdot[idx] = 0.f; }
    if (idx < 9600) agg[idx] = 0.f;
    if (idx >= 4 * Bb * 2400) return;
    int step = idx / (Bb * 2400);
    int r = idx - step * (Bb * 2400);
    int b = r / 2400; int k = r - b * 2400;
    int p = k / 300;  int h = k - p * 300;
    iscale4[idx] = instr[((size_t)b * NI + step) * Hh + h] * psim5[(b * NI + step) * 8 + p];
}

__global__ void edge_msg_k(const int* __restrict__ ei, const float* __restrict__ es,
                           const float* __restrict__ dist, float* __restrict__ msgdot)
{
    int e = blockIdx.x * 256 + threadIdx.x;
    if (e < Ee){
        int s = ei[e];
        int d = ei[Ee + e];
        atomicAdd(&msgdot[d], dist[s] * es[e]);
    }
}

// seg_update also re-zeros its msgdot range for the next iteration.
__global__ __launch_bounds__(256) void seg_update_k(
    const float* __restrict__ nscore, float* __restrict__ msgdot,
    const float* __restrict__ rsim5, int step, float* __restrict__ dist)
{
    int b = blockIdx.x, t = threadIdx.x;
    __shared__ float red[256];
    int n0 = b * NPG;
    float a1 = nscore[n0 + t], a2 = nscore[n0 + 256 + t];
    float m1 = msgdot[n0 + t], m2 = msgdot[n0 + 256 + t];

    red[t] = fmaxf(a1, a2); __syncthreads();
    for (int s = 128; s > 0; s >>= 1){ if (t < s) red[t] = fmaxf(red[t], red[t+s]); __syncthreads(); }
    float mN = red[0]; __syncthreads();
    float e1 = expf(a1 - mN), e2 = expf(a2 - mN);
    red[t] = e1 + e2; __syncthreads();
    for (int s = 128; s > 0; s >>= 1){ if (t < s) red[t] += red[t+s]; __syncthreads(); }
    float sN = red[0]; __syncthreads();

    red[t] = fmaxf(m1, m2); __syncthreads();
    for (int s = 128; s > 0; s >>= 1){ if (t < s) red[t] = fmaxf(red[t], red[t+s]); __syncthreads(); }
    float mM = red[0]; __syncthreads();
    float f1 = expf(m1 - mM), f2 = expf(m2 - mM);
    red[t] = f1 + f2; __syncthreads();
    for (int s = 128; s > 0; s >>= 1){ if (t < s) red[t] += red[t+s]; __syncthreads(); }
    float sM = red[0];

    float rs = rsim5[b * NI + step];
    dist[n0 + t]       = rs * (f1 / sM) + (1.f - rs) * (e1 / sN);
    dist[n0 + 256 + t] = rs * (f2 / sM) + (1.f - rs) * (e2 / sN);
    msgdot[n0 + t] = 0.f;
    msgdot[n0 + 256 + t] = 0.f;
}

// final aggregation (bf16 attrs)
__global__ __launch_bounds__(320) void final_agg_bf_k(
    const float* __restrict__ psim5, const float* __restrict__ dist,
    const unsigned short* __restrict__ nab, float* __restrict__ agg)
{
    int chunk = blockIdx.x;
    int b = blockIdx.y;
    int h = threadIdx.x;
    if (h >= Hh) return;
    float ps[8];
    #pragma unroll
    for (int p = 0; p < 8; p++) ps[p] = psim5[(b * NI + 4) * 8 + p];
    float acc = 0.f;
    for (int i = 0; i < 32; i++){
        int n = b * NPG + chunk * 32 + i;
        const unsigned short* row = nab + (size_t)n * 2400;
        float wsum = 0.f;
        #pragma unroll
        for (int p = 0; p < 8; p++) wsum += ps[p] * bf2f(row[p * Hh + h]);
        acc += dist[n] * wsum;
    }
    atomicAdd(&agg[b * Hh + h], acc);
}
__global__ __launch_bounds__(320) void final_agg_k(
    const float* __restrict__ psim5, const float* __restrict__ dist,
    const float* __restrict__ na, float* __restrict__ agg)
{
    int chunk = blockIdx.x;
    int b = blockIdx.y;
    int h = threadIdx.x;
    if (h >= Hh) return;
    float ps[8];
    #pragma unroll
    for (int p = 0; p < 8; p++) ps[p] = psim5[(b * NI + 4) * 8 + p];
    float acc = 0.f;
    for (int i = 0; i < 32; i++){
        int n = b * NPG + chunk * 32 + i;
        const float* row = na + (size_t)n * Pp * Hh;
        float wsum = 0.f;
        #pragma unroll
        for (int p = 0; p < 8; p++) wsum += ps[p] * row[p * Hh + h];
        acc += dist[n] * wsum;
    }
    atomicAdd(&agg[b * Hh + h], acc);
}

// fc1 with fused feats, elu epilogue
__global__ void fc1_k(const float* __restrict__ enc, const float* __restrict__ agg,
                      const float* __restrict__ W, const float* __restrict__ bias,
                      float* __restrict__ z)
{
    int idx = blockIdx.x * 256 + threadIdx.x;
    if (idx >= Bb * 600) return;
    int m = idx / 600, j = idx - m * 600;
    const float* wr = W + (size_t)j * 600;
    float s = 0.f;
    for (int k = 0; k < 300; k++) s += enc[m * 300 + k] * wr[k];
    for (int k = 0; k < 300; k++) s += agg[m * 300 + k] * wr[300 + k];
    z[idx] = eluf(s + bias[j]);
}

__global__ void fc2_k(const float* __restrict__ z, const float* __restrict__ W,
                      const float* __restrict__ bias, float* __restrict__ out)
{
    int idx = blockIdx.x * 256 + threadIdx.x;
    if (idx >= Bb * 1845) return;
    int m = idx / 1845, j = idx - m * 1845;
    const float* wr = W + (size_t)j * 600;
    const float* zr = z + m * 600;
    float s = 0.f;
    for (int k = 0; k < 600; k++) s += zr[k] * wr[k];
    out[idx] = s + bias[j];
}

// ---------------------------------------------------------------------------
extern "C" void kernel_launch(void* const* d_in, const int* in_sizes, int n_in,
                              void* d_out, int out_size, void* d_ws, size_t ws_size,
                              hipStream_t stream)
{
    const float* questions      = (const float*)d_in[0];
    const int*   lengths        = (const int*)  d_in[1];
    const int*   node_indices   = (const int*)  d_in[2];
    const int*   edge_indices   = (const int*)  d_in[3];
    const int*   edge_batch     = (const int*)  d_in[4];
    const float* node_attrs     = (const float*)d_in[5];
    const float* edge_attrs     = (const float*)d_in[6];
    const float* concept_vocab  = (const float*)d_in[7];
    const float* prop_emb       = (const float*)d_in[8];
    const float* tagger_default = (const float*)d_in[9];
    const float* tagger_weight  = (const float*)d_in[10];
    const float* lstm_Wih       = (const float*)d_in[11];
    const float* lstm_Whh       = (const float*)d_in[12];
    const float* lstm_bih       = (const float*)d_in[13];
    const float* lstm_bhh       = (const float*)d_in[14];
    const float* rnn_Wih        = (const float*)d_in[15];
    const float* rnn_Whh        = (const float*)d_in[16];
    const float* rnn_bih        = (const float*)d_in[17];
    const float* rnn_bhh        = (const float*)d_in[18];
    const float* Wnp            = (const float*)d_in[19];
    const float* Wedge          = (const float*)d_in[20];
    const float* w_nscore       = (const float*)d_in[21];
    const float* w_rscore       = (const float*)d_in[22];
    const float* fc1_W          = (const float*)d_in[23];
    const float* fc1_b          = (const float*)d_in[24];
    const float* fc2_W          = (const float*)d_in[25];
    const float* fc2_b          = (const float*)d_in[26];
    float* outf = (float*)d_out;

    float* ws = (float*)d_ws;
    size_t off = 0;
    auto alloc = [&](size_t n){ size_t r = off; off += (n + 63) & ~(size_t)63; return r; };
    size_t o_q2     = alloc(960 * 300);
    size_t o_sim    = alloc((size_t)960 * 2001);
    size_t o_tagged = alloc(960 * 300);
    size_t o_xw     = alloc((size_t)960 * 1200);
    size_t o_enc    = alloc(9600);
    size_t o_hidden = alloc(48000);
    size_t o_instr  = alloc(48000);
    size_t o_psim5  = alloc(1280);
    size_t o_rsim5  = alloc(160);
    size_t o_iscl4  = alloc((size_t)4 * Bb * 2400);
    size_t o_nsc4   = alloc((size_t)4 * Nn);
    size_t o_es4    = alloc((size_t)4 * Ee);
    size_t o_msgdot = alloc(Nn);
    size_t o_dist   = alloc(Nn);
    size_t o_agg    = alloc(9600);
    size_t o_z      = alloc(19200);
    size_t o_btn    = alloc((size_t)304 * 2400 / 2);
    size_t o_bte    = alloc((size_t)304 * 320 / 2);
    size_t o_wn     = alloc(304);
    size_t o_wr     = alloc(304);
    size_t o_wlstm  = alloc(180000);
    size_t o_rwhhT  = alloc(90000);
    size_t o_rwihT  = alloc(90000);
    size_t o_btq    = alloc((size_t)304 * 320 / 2);
    size_t o_btv    = alloc((size_t)2128 * 320 / 2);
    size_t o_btc    = alloc((size_t)304 * 2016 / 2);
    size_t o_btw    = alloc((size_t)1216 * 320 / 2);
    size_t o_nab    = alloc((size_t)Nn * 2400 / 2);
    size_t o_eab    = alloc((size_t)Ee * 320 / 2);
    const bool bigws = ws_size >= off * sizeof(float);

    unsigned short* btn = (unsigned short*)(ws + o_btn);
    unsigned short* bte = (unsigned short*)(ws + o_bte);
    unsigned short* wlstm = (unsigned short*)(ws + o_wlstm);
    unsigned short* btq = (unsigned short*)(ws + o_btq);
    unsigned short* btv = (unsigned short*)(ws + o_btv);
    unsigned short* btc = (unsigned short*)(ws + o_btc);
    unsigned short* btw = (unsigned short*)(ws + o_btw);
    unsigned short* nab = (unsigned short*)(ws + o_nab);
    unsigned short* eab = (unsigned short*)(ws + o_eab);

    // ---- one prep launch (all weight tables) + one convert launch ----
    prep_all_k<<<(R_TOTAL + 255)/256, 256, 0, stream>>>(
        Wnp, Wedge, tagger_weight, concept_vocab, tagger_default,
        lstm_Wih, lstm_Whh, rnn_Whh, rnn_Wih, w_nscore, w_rscore,
        btn, bte, btq, btv, btc, btw, wlstm,
        ws + o_rwhhT, ws + o_rwihT, ws + o_wn, ws + o_wr);
    if (bigws)
        cvt_both_k<<<2048, 256, 0, stream>>>(node_attrs, edge_attrs, nab, eab);

    // ---- tagger chain ----
    mfma_gemm_k<<<dim3(15,1), 256, 0, stream>>>(
        questions, 300, 300, 10, btq, 320, 300, ws + o_q2, 300, nullptr, nullptr);
    mfma_gemm_k<<<dim3(15,7), 256, 0, stream>>>(
        ws + o_q2, 300, 300, 10, btv, 320, 2001, ws + o_sim, 2001, nullptr, nullptr);
    softmax_rows_k<<<960, 256, 0, stream>>>(ws + o_sim, 2001);
    mfma_gemm_k<<<dim3(15,1), 256, 0, stream>>>(
        ws + o_sim, 2001, 2000, 63, btc, 2016, 300, ws + o_tagged, 300,
        ws + o_sim + 2000, questions);

    // ---- LSTM ----
    mfma_gemm_k<<<dim3(15,4), 256, 0, stream>>>(
        ws + o_tagged, 300, 300, 10, btw, 320, 1200, ws + o_xw, 1200, nullptr, nullptr);
    lstm_fast_k<<<Bb, 640, 0, stream>>>(ws + o_xw, wlstm, lstm_bih, lstm_bhh,
                                        lengths, ws + o_enc);

    // ---- RNN + instructions ----
    rnn_all_k<<<Bb, 320, 0, stream>>>(ws + o_enc, ws + o_rwihT, ws + o_rwhhT,
                                      rnn_bih, rnn_bhh, ws + o_hidden);
    scores_instr_k<<<40, 256, 0, stream>>>(ws + o_hidden, ws + o_tagged, lengths, ws + o_instr);

    // ---- hoisted data-parallel phase (batched over steps via blockIdx.y) ----
    prop_softmax_all_k<<<40, 256, 0, stream>>>(ws + o_instr, prop_emb, ws + o_psim5, ws + o_rsim5);
    iscale4_k<<<(4*Bb*2400 + 255)/256, 256, 0, stream>>>(
        ws + o_instr, ws + o_psim5, ws + o_iscl4, ws + o_dist, ws + o_msgdot, ws + o_agg);
    if (bigws) {
        mfma_node_k<<<dim3(Nn/64, 4), 256, 0, stream>>>(
            nab, btn, ws + o_iscl4, node_indices, ws + o_wn, ws + o_nsc4);
        mfma_edge_k<<<dim3(Ee/64, 4), 256, 0, stream>>>(
            eab, bte, ws + o_instr, edge_batch, ws + o_wr, ws + o_es4);
    } else {
        mfma_node_f_k<<<dim3(Nn/64, 4), 256, 0, stream>>>(
            node_attrs, btn, ws + o_iscl4, node_indices, ws + o_wn, ws + o_nsc4);
        mfma_edge_f_k<<<dim3(Ee/64, 4), 256, 0, stream>>>(
            edge_attrs, bte, ws + o_instr, edge_batch, ws + o_wr, ws + o_es4);
    }

    // ---- serial message-passing tail ----
    for (int step = 0; step < 4; step++){
        edge_msg_k<<<512, 256, 0, stream>>>(edge_indices, ws + o_es4 + (size_t)step * Ee,
                                            ws + o_dist, ws + o_msgdot);
        seg_update_k<<<32, 256, 0, stream>>>(ws + o_nsc4 + (size_t)step * Nn, ws + o_msgdot,
                                             ws + o_rsim5, step, ws + o_dist);
    }

    // ---- final aggregation + FCs ----
    if (bigws)
        final_agg_bf_k<<<dim3(16,32), 320, 0, stream>>>(ws + o_psim5, ws + o_dist, nab, ws + o_agg);
    else
        final_agg_k<<<dim3(16,32), 320, 0, stream>>>(ws + o_psim5, ws + o_dist, node_attrs, ws + o_agg);
    fc1_k<<<75, 256, 0, stream>>>(ws + o_enc, ws + o_agg, fc1_W, fc1_b, ws + o_z);
    fc2_k<<<(Bb*1845 + 255)/256, 256, 0, stream>>>(ws + o_z, fc2_W, fc2_b, outf);
}